// Round 1
// baseline (2995.808 us; speedup 1.0000x reference)
//
#include <hip/hip_runtime.h>
#include <math.h>

#define NN   20000
#define EE   320000
#define HID  256
#define K1   800      // 3*HID + 32 RBF
#define KU   512      // 2*HID

// XOR swizzle on the edge index (bits 2..4) to break bank conflicts on the
// transposed activation buffer. Preserves float4 contiguity/alignment.
#define SWZ(k, e) ((e) ^ ((((k) >> 2) & 7) << 2))

__device__ __forceinline__ float silu_f(float x) {
    return x / (1.0f + __expf(-x));
}

// ---------------------------------------------------------------------------
// Edge kernel: 32 edges per block, 256 threads.
//   m    = silu(m_in @ W1m + b1m)   K=800
//   m_ij = silu(m @ W2m + b2m)      K=256
//   atomicAdd into seg[dst], cnt[dst]
// Micro-tile: 8 rows (edges) x 4 cols per thread; A-reads are wave-uniform.
// ---------------------------------------------------------------------------
__global__ __launch_bounds__(256) void edge_kernel(
    const float* __restrict__ h, const float* __restrict__ pos,
    const int* __restrict__ ei, const int* __restrict__ etype,
    const float* __restrict__ emb,
    const float* __restrict__ W1, const float* __restrict__ b1,
    const float* __restrict__ W2, const float* __restrict__ b2,
    float* __restrict__ seg, float* __restrict__ cnt)
{
    __shared__ float A1T[16][32];    // 2 KB   (transposed m_in chunk)
    __shared__ float Bt[16][256];    // 16 KB  (W tile)
    __shared__ float A2T[256][32];   // 32 KB  (transposed m, swizzled)
    __shared__ float distS[32];
    __shared__ int   srcS[32], dstS[32], etS[32];

    const int tid = threadIdx.x;
    const int e0  = blockIdx.x * 32;

    if (tid < 32) {
        const int e = e0 + tid;
        const int s = ei[e];
        const int d = ei[EE + e];
        srcS[tid] = s; dstS[tid] = d; etS[tid] = etype[e];
        const float dx = pos[3*s+0] - pos[3*d+0];
        const float dy = pos[3*s+1] - pos[3*d+1];
        const float dz = pos[3*s+2] - pos[3*d+2];
        distS[tid] = sqrtf(dx*dx + dy*dy + dz*dz);
        atomicAdd(&cnt[d], 1.0f);
    }
    __syncthreads();

    const int c0 = (tid & 63) * 4;   // output column base (0..252)
    const int r0 = (tid >> 6) * 8;   // output row base, uniform per wave

    float acc[8][4];
    #pragma unroll
    for (int i = 0; i < 8; ++i)
        #pragma unroll
        for (int j = 0; j < 4; ++j) acc[i][j] = 0.0f;

    const float step  = 6.0f / 31.0f;
    const float gamma = 1.0f / (step * step);

    // ---------------- GEMM 1: K = 800 ----------------
    for (int k0 = 0; k0 < K1; k0 += 16) {
        // stage A1T: 16 k's x 32 edges; 128 threads x float4
        if (tid < 128) {
            const int e = tid >> 2;          // edge 0..31
            const int q = (tid & 3) * 4;     // k offset within chunk
            const int k = k0 + q;
            float4 v;
            if (k < 256) {
                v = *(const float4*)&h[(size_t)srcS[e]*HID + k];
            } else if (k < 512) {
                v = *(const float4*)&h[(size_t)dstS[e]*HID + (k - 256)];
            } else if (k < 768) {
                v = *(const float4*)&emb[(size_t)etS[e]*HID + (k - 512)];
            } else {
                const float de = distS[e];
                const float t0 = de - step*(float)(k-768);
                const float t1 = de - step*(float)(k-767);
                const float t2 = de - step*(float)(k-766);
                const float t3 = de - step*(float)(k-765);
                v = make_float4(__expf(-gamma*t0*t0), __expf(-gamma*t1*t1),
                                __expf(-gamma*t2*t2), __expf(-gamma*t3*t3));
            }
            A1T[q+0][e] = v.x; A1T[q+1][e] = v.y;
            A1T[q+2][e] = v.z; A1T[q+3][e] = v.w;
        }
        // stage Bt: W1m rows k0..k0+15
        #pragma unroll
        for (int p = 0; p < 4; ++p) {
            const int idx = p*256 + tid;       // float4 index
            const int k   = idx >> 6;          // 64 float4 per row
            const int n   = (idx & 63) * 4;
            *(float4*)&Bt[k][n] = *(const float4*)&W1[(size_t)(k0+k)*HID + n];
        }
        __syncthreads();
        #pragma unroll
        for (int kk = 0; kk < 16; ++kk) {
            const float4 b  = *(const float4*)&Bt[kk][c0];
            const float4 a0 = *(const float4*)&A1T[kk][r0];
            const float4 a1 = *(const float4*)&A1T[kk][r0+4];
            const float a[8] = {a0.x,a0.y,a0.z,a0.w,a1.x,a1.y,a1.z,a1.w};
            #pragma unroll
            for (int i = 0; i < 8; ++i) {
                acc[i][0] = fmaf(a[i], b.x, acc[i][0]);
                acc[i][1] = fmaf(a[i], b.y, acc[i][1]);
                acc[i][2] = fmaf(a[i], b.z, acc[i][2]);
                acc[i][3] = fmaf(a[i], b.w, acc[i][3]);
            }
        }
        __syncthreads();
    }

    // bias + silu -> A2T (swizzled transpose), reset acc
    {
        const float4 b1v = *(const float4*)&b1[c0];
        const float bb[4] = {b1v.x, b1v.y, b1v.z, b1v.w};
        #pragma unroll
        for (int j = 0; j < 4; ++j) {
            const int k = c0 + j;
            #pragma unroll
            for (int i = 0; i < 8; ++i) {
                const float x = acc[i][j] + bb[j];
                A2T[k][SWZ(k, r0+i)] = silu_f(x);
                acc[i][j] = 0.0f;
            }
        }
    }
    __syncthreads();

    // ---------------- GEMM 2: K = 256 ----------------
    for (int k0 = 0; k0 < HID; k0 += 16) {
        #pragma unroll
        for (int p = 0; p < 4; ++p) {
            const int idx = p*256 + tid;
            const int k   = idx >> 6;
            const int n   = (idx & 63) * 4;
            *(float4*)&Bt[k][n] = *(const float4*)&W2[(size_t)(k0+k)*HID + n];
        }
        __syncthreads();
        #pragma unroll
        for (int kk = 0; kk < 16; ++kk) {
            const int K = k0 + kk;
            const float4 b  = *(const float4*)&Bt[kk][c0];
            const float4 a0 = *(const float4*)&A2T[K][SWZ(K, r0)];
            const float4 a1 = *(const float4*)&A2T[K][SWZ(K, r0+4)];
            const float a[8] = {a0.x,a0.y,a0.z,a0.w,a1.x,a1.y,a1.z,a1.w};
            #pragma unroll
            for (int i = 0; i < 8; ++i) {
                acc[i][0] = fmaf(a[i], b.x, acc[i][0]);
                acc[i][1] = fmaf(a[i], b.y, acc[i][1]);
                acc[i][2] = fmaf(a[i], b.z, acc[i][2]);
                acc[i][3] = fmaf(a[i], b.w, acc[i][3]);
            }
        }
        __syncthreads();
    }

    // bias + silu + atomic scatter to seg[dst]
    {
        const float4 b2v = *(const float4*)&b2[c0];
        const float bb[4] = {b2v.x, b2v.y, b2v.z, b2v.w};
        #pragma unroll
        for (int i = 0; i < 8; ++i) {
            const int d = dstS[r0 + i];
            float* outp = &seg[(size_t)d*HID + c0];
            #pragma unroll
            for (int j = 0; j < 4; ++j) {
                const float x = acc[i][j] + bb[j];
                atomicAdd(&outp[j], silu_f(x));
            }
        }
    }
}

// ---------------------------------------------------------------------------
// Node kernel: 32 nodes per block.
//   u   = silu([h, seg/cnt] @ W1u + b1u)   K=512
//   upd = u @ W2u + b2u                    K=256
//   out = ntype==1 ? LN(h+upd)*g+b : h
// ---------------------------------------------------------------------------
__global__ __launch_bounds__(256) void node_kernel(
    const float* __restrict__ h, const float* __restrict__ seg,
    const float* __restrict__ cnt, const int* __restrict__ ntype,
    const float* __restrict__ W1, const float* __restrict__ b1,
    const float* __restrict__ W2, const float* __restrict__ b2,
    const float* __restrict__ lng, const float* __restrict__ lnb,
    float* __restrict__ out)
{
    __shared__ float A1T[16][32];
    __shared__ float Bt[16][256];
    __shared__ float A2T[256][32];
    __shared__ float invS[32];

    const int tid = threadIdx.x;
    const int n0  = blockIdx.x * 32;

    if (tid < 32) {
        invS[tid] = 1.0f / fmaxf(cnt[n0 + tid], 1.0f);
    }
    __syncthreads();

    const int c0 = (tid & 63) * 4;
    const int r0 = (tid >> 6) * 8;

    float acc[8][4];
    #pragma unroll
    for (int i = 0; i < 8; ++i)
        #pragma unroll
        for (int j = 0; j < 4; ++j) acc[i][j] = 0.0f;

    // ---------------- GEMM 1: K = 512 ----------------
    for (int k0 = 0; k0 < KU; k0 += 16) {
        if (tid < 128) {
            const int e = tid >> 2;
            const int q = (tid & 3) * 4;
            const int k = k0 + q;
            float4 v;
            if (k < 256) {
                v = *(const float4*)&h[(size_t)(n0+e)*HID + k];
            } else {
                v = *(const float4*)&seg[(size_t)(n0+e)*HID + (k - 256)];
                const float ic = invS[e];
                v.x *= ic; v.y *= ic; v.z *= ic; v.w *= ic;
            }
            A1T[q+0][e] = v.x; A1T[q+1][e] = v.y;
            A1T[q+2][e] = v.z; A1T[q+3][e] = v.w;
        }
        #pragma unroll
        for (int p = 0; p < 4; ++p) {
            const int idx = p*256 + tid;
            const int k   = idx >> 6;
            const int n   = (idx & 63) * 4;
            *(float4*)&Bt[k][n] = *(const float4*)&W1[(size_t)(k0+k)*HID + n];
        }
        __syncthreads();
        #pragma unroll
        for (int kk = 0; kk < 16; ++kk) {
            const float4 b  = *(const float4*)&Bt[kk][c0];
            const float4 a0 = *(const float4*)&A1T[kk][r0];
            const float4 a1 = *(const float4*)&A1T[kk][r0+4];
            const float a[8] = {a0.x,a0.y,a0.z,a0.w,a1.x,a1.y,a1.z,a1.w};
            #pragma unroll
            for (int i = 0; i < 8; ++i) {
                acc[i][0] = fmaf(a[i], b.x, acc[i][0]);
                acc[i][1] = fmaf(a[i], b.y, acc[i][1]);
                acc[i][2] = fmaf(a[i], b.z, acc[i][2]);
                acc[i][3] = fmaf(a[i], b.w, acc[i][3]);
            }
        }
        __syncthreads();
    }

    {
        const float4 b1v = *(const float4*)&b1[c0];
        const float bb[4] = {b1v.x, b1v.y, b1v.z, b1v.w};
        #pragma unroll
        for (int j = 0; j < 4; ++j) {
            const int k = c0 + j;
            #pragma unroll
            for (int i = 0; i < 8; ++i) {
                const float x = acc[i][j] + bb[j];
                A2T[k][SWZ(k, r0+i)] = silu_f(x);
                acc[i][j] = 0.0f;
            }
        }
    }
    __syncthreads();

    // ---------------- GEMM 2: K = 256 ----------------
    for (int k0 = 0; k0 < HID; k0 += 16) {
        #pragma unroll
        for (int p = 0; p < 4; ++p) {
            const int idx = p*256 + tid;
            const int k   = idx >> 6;
            const int n   = (idx & 63) * 4;
            *(float4*)&Bt[k][n] = *(const float4*)&W2[(size_t)(k0+k)*HID + n];
        }
        __syncthreads();
        #pragma unroll
        for (int kk = 0; kk < 16; ++kk) {
            const int K = k0 + kk;
            const float4 b  = *(const float4*)&Bt[kk][c0];
            const float4 a0 = *(const float4*)&A2T[K][SWZ(K, r0)];
            const float4 a1 = *(const float4*)&A2T[K][SWZ(K, r0+4)];
            const float a[8] = {a0.x,a0.y,a0.z,a0.w,a1.x,a1.y,a1.z,a1.w};
            #pragma unroll
            for (int i = 0; i < 8; ++i) {
                acc[i][0] = fmaf(a[i], b.x, acc[i][0]);
                acc[i][1] = fmaf(a[i], b.y, acc[i][1]);
                acc[i][2] = fmaf(a[i], b.z, acc[i][2]);
                acc[i][3] = fmaf(a[i], b.w, acc[i][3]);
            }
        }
        __syncthreads();
    }

    // ------------- epilogue: h+upd, conditional LayerNorm -------------
    {
        const float4 b2v = *(const float4*)&b2[c0];
        const float bb[4] = {b2v.x, b2v.y, b2v.z, b2v.w};
        float4 hv[8];
        #pragma unroll
        for (int i = 0; i < 8; ++i) {
            hv[i] = *(const float4*)&h[(size_t)(n0+r0+i)*HID + c0];
            acc[i][0] = hv[i].x + acc[i][0] + bb[0];   // acc := x = h + upd
            acc[i][1] = hv[i].y + acc[i][1] + bb[1];
            acc[i][2] = hv[i].z + acc[i][2] + bb[2];
            acc[i][3] = hv[i].w + acc[i][3] + bb[3];
        }
        // per-row mean / var across 256 cols (one wave owns rows r0..r0+7)
        float s1[8], s2[8];
        #pragma unroll
        for (int i = 0; i < 8; ++i) {
            s1[i] = acc[i][0] + acc[i][1] + acc[i][2] + acc[i][3];
            s2[i] = acc[i][0]*acc[i][0] + acc[i][1]*acc[i][1]
                  + acc[i][2]*acc[i][2] + acc[i][3]*acc[i][3];
        }
        #pragma unroll
        for (int off = 32; off >= 1; off >>= 1) {
            #pragma unroll
            for (int i = 0; i < 8; ++i) {
                s1[i] += __shfl_xor(s1[i], off, 64);
                s2[i] += __shfl_xor(s2[i], off, 64);
            }
        }
        const float4 gv = *(const float4*)&lng[c0];
        const float4 bv = *(const float4*)&lnb[c0];
        const float g[4] = {gv.x, gv.y, gv.z, gv.w};
        const float bb2[4] = {bv.x, bv.y, bv.z, bv.w};
        #pragma unroll
        for (int i = 0; i < 8; ++i) {
            const int n = n0 + r0 + i;
            const bool lig = (ntype[n] == 1);
            float4 y;
            if (lig) {
                const float mu  = s1[i] * (1.0f/256.0f);
                const float var = s2[i] * (1.0f/256.0f) - mu*mu;
                const float rs  = rsqrtf(var + 1e-5f);
                y.x = (acc[i][0] - mu) * rs * g[0] + bb2[0];
                y.y = (acc[i][1] - mu) * rs * g[1] + bb2[1];
                y.z = (acc[i][2] - mu) * rs * g[2] + bb2[2];
                y.w = (acc[i][3] - mu) * rs * g[3] + bb2[3];
            } else {
                y = hv[i];
            }
            *(float4*)&out[(size_t)n*HID + c0] = y;
        }
    }
}

extern "C" void kernel_launch(void* const* d_in, const int* in_sizes, int n_in,
                              void* d_out, int out_size, void* d_ws, size_t ws_size,
                              hipStream_t stream) {
    (void)in_sizes; (void)n_in; (void)out_size; (void)ws_size;
    const float* h    = (const float*)d_in[0];
    const float* pos  = (const float*)d_in[1];
    const int*   ei   = (const int*)  d_in[2];
    const int*   et   = (const int*)  d_in[3];
    const int*   nt   = (const int*)  d_in[4];
    const float* emb  = (const float*)d_in[5];
    const float* W1m  = (const float*)d_in[6];
    const float* b1m  = (const float*)d_in[7];
    const float* W2m  = (const float*)d_in[8];
    const float* b2m  = (const float*)d_in[9];
    const float* W1u  = (const float*)d_in[10];
    const float* b1u  = (const float*)d_in[11];
    const float* W2u  = (const float*)d_in[12];
    const float* b2u  = (const float*)d_in[13];
    const float* lng  = (const float*)d_in[14];
    const float* lnb  = (const float*)d_in[15];
    float* out = (float*)d_out;

    float* seg = (float*)d_ws;               // [NN, HID]
    float* cnt = seg + (size_t)NN * HID;     // [NN]

    // zero the aggregation buffers (ws is poisoned 0xAA before every launch)
    hipMemsetAsync(d_ws, 0, ((size_t)NN * HID + NN) * sizeof(float), stream);

    edge_kernel<<<EE / 32, 256, 0, stream>>>(h, pos, ei, et, emb,
                                             W1m, b1m, W2m, b2m, seg, cnt);
    node_kernel<<<NN / 32, 256, 0, stream>>>(h, seg, cnt, nt,
                                             W1u, b1u, W2u, b2u, lng, lnb, out);
}

// Round 3
// 1015.156 us; speedup vs baseline: 2.9511x; 2.9511x over previous
//
#include <hip/hip_runtime.h>
#include <hip/hip_fp16.h>
#include <math.h>

#define NN   20000
#define EE   320000
#define HID  256
#define GAMMA_C ((31.0f/6.0f)*(31.0f/6.0f))   // 1/step^2, step = 6/31

typedef __attribute__((ext_vector_type(8)))  short    short8;   // 8 bf16 bits
typedef __attribute__((ext_vector_type(8)))  _Float16 half8;    // 8 fp16
typedef __attribute__((ext_vector_type(16))) float    f32x16;

__device__ __forceinline__ float silu_f(float x) {
    return x / (1.0f + __expf(-x));
}

// fp32 -> bf16 RNE bits
__device__ __forceinline__ short bf_hi(float x) {
    unsigned u = __float_as_uint(x);
    return (short)((u + 0x7fffu + ((u >> 16) & 1u)) >> 16);
}
__device__ __forceinline__ float bf_tof(short b) {
    return __uint_as_float(((unsigned)(unsigned short)b) << 16);
}
__device__ __forceinline__ void cvt_bf16_pair(float x, short* hi, short* lo) {
    short h = bf_hi(x);
    *hi = h;
    *lo = bf_hi(x - bf_tof(h));
}
__device__ __forceinline__ void cvt_f16_pair(float x, short* hi, short* lo) {
    __half h = __float2half_rn(x);
    *hi = (short)__half_as_ushort(h);
    *lo = (short)__half_as_ushort(__float2half_rn(x - __half2float(h)));
}
__device__ __forceinline__ short f16_bits(float x) {
    return (short)__half_as_ushort(__float2half_rn(x));
}

// async global->LDS, 16B per lane; LDS dest = uniform base + lane*16
typedef __attribute__((address_space(1))) const void GV;
typedef __attribute__((address_space(3))) void LV;
__device__ __forceinline__ void gll16(const void* g, void* l) {
    __builtin_amdgcn_global_load_lds((GV*)g, (LV*)l, 16, 0, 0);
}

// All LDS tiles use 128B rows = 8 slots of 16B; physical slot = sigma ^ (row&7).
// Same swizzle is applied on the global SOURCE during staging (rule #21).
__device__ __forceinline__ short8 ldsfrag(const short* t, int row, int sg) {
    int s = sg ^ (row & 7);
    return *(const short8*)&t[row * 64 + s * 8];
}
__device__ __forceinline__ half8 ldsfragh(const short* t, int row, int sg) {
    int s = sg ^ (row & 7);
    return *(const half8*)&t[row * 64 + s * 8];
}

// ---------------------------------------------------------------------------
// prep: fp32 -> split planes.  bf16 pairs: h, emb, W1m^T, W1u^T.
//       f16 pairs: W2m^T, W2u^T (feed the f16 GEMM2s).
// ---------------------------------------------------------------------------
#define S0 (NN*HID)     // h        5,120,000
#define S1 (2*HID)      // emb      512
#define S2 (256*800)    // W1t      204,800
#define S3 (256*256)    // W2t      65,536
#define S4 (256*512)    // W1ut     131,072
#define S5 (256*256)    // W2ut     65,536
#define PREP_TOTAL (S0+S1+S2+S3+S4+S5)   // 5,587,456 = 21826*256

__global__ __launch_bounds__(256) void prep_all(
    const float* __restrict__ h, const float* __restrict__ emb,
    const float* __restrict__ W1m, const float* __restrict__ W2m,
    const float* __restrict__ W1u, const float* __restrict__ W2u,
    short* __restrict__ hpl, short* __restrict__ embpl,
    short* __restrict__ w1t, short* __restrict__ w2t,
    short* __restrict__ w1ut, short* __restrict__ w2ut)
{
    int i = blockIdx.x * 256 + threadIdx.x;
    float x; short *hi, *lo; int o; int f16 = 0;
    if (i < S0)              { x = h[i];   hi = hpl;   lo = hpl + S0;   o = i; }
    else if ((i -= S0) < S1) { x = emb[i]; hi = embpl; lo = embpl + S1; o = i; }
    else if ((i -= S1) < S2) { int n = i / 800, k = i - n * 800;
                               x = W1m[k * 256 + n]; hi = w1t; lo = w1t + S2; o = i; }
    else if ((i -= S2) < S3) { int n = i >> 8, k = i & 255;
                               x = W2m[k * 256 + n]; hi = w2t; lo = w2t + S3; o = i; f16 = 1; }
    else if ((i -= S3) < S4) { int n = i >> 9, k = i & 511;
                               x = W1u[k * 256 + n]; hi = w1ut; lo = w1ut + S4; o = i; }
    else if ((i -= S4) < S5) { int n = i >> 8, k = i & 255;
                               x = W2u[k * 256 + n]; hi = w2ut; lo = w2ut + S5; o = i; f16 = 1; }
    else return;
    short hb, lb;
    if (f16) cvt_f16_pair(x, &hb, &lb); else cvt_bf16_pair(x, &hb, &lb);
    hi[o] = hb; lo[o] = lb;
}

// ---------------------------------------------------------------------------
// edge_mlp1: m = silu(m_in @ W1m + b1m), stored as fp16 plane.
// Block = 128 edges, 512 thr (8 waves, 2 Mhalf x 4 Nstripe), wave tile 64x64.
// K=800 in 25 chunks of 32; A rows pack [hi q0..3 | lo q0..3] (128B).
// 3-term split MFMA (hi*hi + hi*lo + lo*hi), mfma_f32_32x32x16_bf16.
// ---------------------------------------------------------------------------
__global__ __launch_bounds__(512) void edge_mlp1(
    const short* __restrict__ hpl, const short* __restrict__ embpl,
    const short* __restrict__ w1t, const float* __restrict__ b1,
    const float* __restrict__ pos, const int* __restrict__ ei,
    const int* __restrict__ etype,
    short* __restrict__ mhi, float* __restrict__ cnt)
{
    __shared__ __align__(16) short At[128 * 64];   // 16 KB
    __shared__ __align__(16) short Bt[256 * 64];   // 32 KB
    __shared__ int srcS[128], dstS[128], etS[128];
    __shared__ float distS[128];

    const int tid = threadIdx.x, l = tid & 63, w = tid >> 6;
    const int e0 = blockIdx.x * 128;
    const int mh = w >> 2, ns = w & 3;

    if (tid < 128) {
        int s = ei[e0 + tid], d = ei[EE + e0 + tid];
        srcS[tid] = s; dstS[tid] = d; etS[tid] = etype[e0 + tid];
        float dx = pos[3*s]   - pos[3*d];
        float dy = pos[3*s+1] - pos[3*d+1];
        float dz = pos[3*s+2] - pos[3*d+2];
        distS[tid] = sqrtf(dx*dx + dy*dy + dz*dz);
        atomicAdd(&cnt[d], 1.0f);
    }
    __syncthreads();

    f32x16 acc[2][2];
    #pragma unroll
    for (int a = 0; a < 2; ++a)
        #pragma unroll
        for (int b = 0; b < 2; ++b)
            #pragma unroll
            for (int q = 0; q < 16; ++q) acc[a][b][q] = 0.0f;

    for (int c = 0; c < 25; ++c) {
        if (c < 24) {
            // A stage: 16 x 1KB async loads (gathered rows, swizzled source)
            #pragma unroll
            for (int jj = 0; jj < 2; ++jj) {
                int j = w * 2 + jj;
                int row = j * 8 + (l >> 3), s = l & 7;
                int sg = s ^ (row & 7);
                int hl = sg >> 2, q = sg & 3;
                const short* gp;
                if (c < 8)
                    gp = hpl + (size_t)hl * (NN*HID) + (size_t)srcS[row] * HID + c*32 + q*8;
                else if (c < 16)
                    gp = hpl + (size_t)hl * (NN*HID) + (size_t)dstS[row] * HID + (c-8)*32 + q*8;
                else
                    gp = embpl + hl * (2*HID) + etS[row] * HID + (c-16)*32 + q*8;
                gll16(gp, &At[j * 512]);
            }
        } else {
            // RBF chunk (k 768..799): compute + swizzled ds_write
            #pragma unroll
            for (int jj = 0; jj < 2; ++jj) {
                int it = tid * 2 + jj;
                int row = it >> 3, s = it & 7;
                int sg = s ^ (row & 7);
                int hl = sg >> 2, q = sg & 3;
                float d = distS[row];
                short8 v;
                #pragma unroll
                for (int k8 = 0; k8 < 8; ++k8) {
                    float cen = (float)(q * 8 + k8) * (6.0f / 31.0f);
                    float t = d - cen;
                    float f = __expf(-GAMMA_C * t * t);
                    short hb = bf_hi(f);
                    v[k8] = hl ? bf_hi(f - bf_tof(hb)) : hb;
                }
                *(short8*)&At[row * 64 + s * 8] = v;
            }
        }
        // B stage: W1^T tile, 32 x 1KB
        #pragma unroll
        for (int jj = 0; jj < 4; ++jj) {
            int j = w * 4 + jj;
            int n = j * 8 + (l >> 3), s = l & 7;
            int sg = s ^ (n & 7);
            int hl = sg >> 2, q = sg & 3;
            const short* gp = w1t + (size_t)hl * (256*800) + n * 800 + c*32 + q*8;
            gll16(gp, &Bt[j * 512]);
        }
        __syncthreads();
        #pragma unroll
        for (int t2 = 0; t2 < 2; ++t2) {
            short8 aF[2][2], bF[2][2];
            #pragma unroll
            for (int mf = 0; mf < 2; ++mf) {
                int row = mh * 64 + mf * 32 + (l & 31);
                #pragma unroll
                for (int hl = 0; hl < 2; ++hl)
                    aF[mf][hl] = ldsfrag(At, row, hl * 4 + t2 * 2 + (l >> 5));
            }
            #pragma unroll
            for (int nf = 0; nf < 2; ++nf) {
                int n = ns * 64 + nf * 32 + (l & 31);
                #pragma unroll
                for (int hl = 0; hl < 2; ++hl)
                    bF[nf][hl] = ldsfrag(Bt, n, hl * 4 + t2 * 2 + (l >> 5));
            }
            #pragma unroll
            for (int mf = 0; mf < 2; ++mf)
                #pragma unroll
                for (int nf = 0; nf < 2; ++nf) {
                    acc[mf][nf] = __builtin_amdgcn_mfma_f32_32x32x16_bf16(aF[mf][0], bF[nf][0], acc[mf][nf], 0, 0, 0);
                    acc[mf][nf] = __builtin_amdgcn_mfma_f32_32x32x16_bf16(aF[mf][0], bF[nf][1], acc[mf][nf], 0, 0, 0);
                    acc[mf][nf] = __builtin_amdgcn_mfma_f32_32x32x16_bf16(aF[mf][1], bF[nf][0], acc[mf][nf], 0, 0, 0);
                }
        }
        __syncthreads();
    }
    // epilogue: bias + silu -> fp16 m plane
    #pragma unroll
    for (int nf = 0; nf < 2; ++nf) {
        int col = ns * 64 + nf * 32 + (l & 31);
        float bb = b1[col];
        #pragma unroll
        for (int mf = 0; mf < 2; ++mf)
            #pragma unroll
            for (int r = 0; r < 16; ++r) {
                int row = mh * 64 + mf * 32 + (r & 3) + 8 * (r >> 2) + 4 * (l >> 5);
                float v = silu_f(acc[mf][nf][r] + bb);
                mhi[(size_t)(e0 + row) * HID + col] = f16_bits(v);
            }
    }
}

// ---------------------------------------------------------------------------
// edge_mlp2: m_ij = silu(m @ W2m + b2m); atomicAdd into seg[dst].
// A = fp16 m (single), B = fp16 W2^T hi/lo (2-term). K=256 in 4 chunks of 64.
// ---------------------------------------------------------------------------
__global__ __launch_bounds__(512) void edge_mlp2(
    const short* __restrict__ mhi, const short* __restrict__ w2t,
    const float* __restrict__ b2, const int* __restrict__ ei,
    float* __restrict__ seg)
{
    __shared__ __align__(16) short Ah[128 * 64];
    __shared__ __align__(16) short Bh[256 * 64];
    __shared__ __align__(16) short Bl[256 * 64];
    __shared__ int dstS[128];
    const int tid = threadIdx.x, l = tid & 63, w = tid >> 6;
    const int e0 = blockIdx.x * 128;
    const int mh = w >> 2, ns = w & 3;
    if (tid < 128) dstS[tid] = ei[EE + e0 + tid];

    f32x16 acc[2][2];
    #pragma unroll
    for (int a = 0; a < 2; ++a)
        #pragma unroll
        for (int b = 0; b < 2; ++b)
            #pragma unroll
            for (int q = 0; q < 16; ++q) acc[a][b][q] = 0.0f;

    for (int c = 0; c < 4; ++c) {
        #pragma unroll
        for (int jj = 0; jj < 2; ++jj) {
            int j = w * 2 + jj;
            int row = j * 8 + (l >> 3), s = l & 7;
            int sg = s ^ (row & 7);
            gll16(mhi + (size_t)(e0 + row) * HID + c * 64 + sg * 8, &Ah[j * 512]);
        }
        #pragma unroll
        for (int jj = 0; jj < 8; ++jj) {
            int j = w * 8 + jj;
            int hf = j >> 5;
            int n = (j & 31) * 8 + (l >> 3), s = l & 7;
            int sg = s ^ (n & 7);
            const short* gp = w2t + (size_t)hf * (256*256) + n * HID + c * 64 + sg * 8;
            gll16(gp, hf ? &Bl[(j & 31) * 512] : &Bh[(j & 31) * 512]);
        }
        __syncthreads();
        #pragma unroll
        for (int t2 = 0; t2 < 4; ++t2) {
            int sg = t2 * 2 + (l >> 5);
            half8 aF[2], bH[2], bL[2];
            #pragma unroll
            for (int mf = 0; mf < 2; ++mf)
                aF[mf] = ldsfragh(Ah, mh * 64 + mf * 32 + (l & 31), sg);
            #pragma unroll
            for (int nf = 0; nf < 2; ++nf) {
                int n = ns * 64 + nf * 32 + (l & 31);
                bH[nf] = ldsfragh(Bh, n, sg);
                bL[nf] = ldsfragh(Bl, n, sg);
            }
            #pragma unroll
            for (int mf = 0; mf < 2; ++mf)
                #pragma unroll
                for (int nf = 0; nf < 2; ++nf) {
                    acc[mf][nf] = __builtin_amdgcn_mfma_f32_32x32x16_f16(aF[mf], bH[nf], acc[mf][nf], 0, 0, 0);
                    acc[mf][nf] = __builtin_amdgcn_mfma_f32_32x32x16_f16(aF[mf], bL[nf], acc[mf][nf], 0, 0, 0);
                }
        }
        __syncthreads();
    }
    #pragma unroll
    for (int nf = 0; nf < 2; ++nf) {
        int col = ns * 64 + nf * 32 + (l & 31);
        float bb = b2[col];
        #pragma unroll
        for (int mf = 0; mf < 2; ++mf)
            #pragma unroll
            for (int r = 0; r < 16; ++r) {
                int row = mh * 64 + mf * 32 + (r & 3) + 8 * (r >> 2) + 4 * (l >> 5);
                float v = silu_f(acc[mf][nf][r] + bb);
                atomicAdd(&seg[(size_t)dstS[row] * HID + col], v);
            }
    }
}

// ---------------------------------------------------------------------------
// mi_prep: m_i = seg / max(cnt,1) -> bf16 hi/lo planes
// ---------------------------------------------------------------------------
__global__ __launch_bounds__(256) void mi_prep(
    const float* __restrict__ seg, const float* __restrict__ cnt,
    short* __restrict__ mipl)
{
    int i = blockIdx.x * 256 + threadIdx.x;
    int row = i >> 8;
    float v = seg[i] / fmaxf(cnt[row], 1.0f);
    short hb, lb;
    cvt_bf16_pair(v, &hb, &lb);
    mipl[i] = hb;
    mipl[(size_t)NN * HID + i] = lb;
}

// ---------------------------------------------------------------------------
// node_mlp1: u = silu([h, m_i] @ W1u + b1u) -> fp16 plane. K=512, 16 chunks.
// ---------------------------------------------------------------------------
__global__ __launch_bounds__(512) void node_mlp1(
    const short* __restrict__ hpl, const short* __restrict__ mipl,
    const short* __restrict__ w1ut, const float* __restrict__ b1,
    short* __restrict__ u)
{
    __shared__ __align__(16) short At[128 * 64];
    __shared__ __align__(16) short Bt[256 * 64];
    const int tid = threadIdx.x, l = tid & 63, w = tid >> 6;
    const int n0 = blockIdx.x * 128;
    const int mh = w >> 2, ns = w & 3;

    f32x16 acc[2][2];
    #pragma unroll
    for (int a = 0; a < 2; ++a)
        #pragma unroll
        for (int b = 0; b < 2; ++b)
            #pragma unroll
            for (int q = 0; q < 16; ++q) acc[a][b][q] = 0.0f;

    for (int c = 0; c < 16; ++c) {
        #pragma unroll
        for (int jj = 0; jj < 2; ++jj) {
            int j = w * 2 + jj;
            int row = j * 8 + (l >> 3), s = l & 7;
            int sg = s ^ (row & 7);
            int hl = sg >> 2, q = sg & 3;
            int node = min(n0 + row, NN - 1);
            const short* gp = (c < 8)
                ? hpl  + (size_t)hl * (NN*HID) + (size_t)node * HID + c * 32 + q * 8
                : mipl + (size_t)hl * (NN*HID) + (size_t)node * HID + (c - 8) * 32 + q * 8;
            gll16(gp, &At[j * 512]);
        }
        #pragma unroll
        for (int jj = 0; jj < 4; ++jj) {
            int j = w * 4 + jj;
            int n = j * 8 + (l >> 3), s = l & 7;
            int sg = s ^ (n & 7);
            int hl = sg >> 2, q = sg & 3;
            const short* gp = w1ut + (size_t)hl * (256*512) + n * 512 + c * 32 + q * 8;
            gll16(gp, &Bt[j * 512]);
        }
        __syncthreads();
        #pragma unroll
        for (int t2 = 0; t2 < 2; ++t2) {
            short8 aF[2][2], bF[2][2];
            #pragma unroll
            for (int mf = 0; mf < 2; ++mf) {
                int row = mh * 64 + mf * 32 + (l & 31);
                #pragma unroll
                for (int hl = 0; hl < 2; ++hl)
                    aF[mf][hl] = ldsfrag(At, row, hl * 4 + t2 * 2 + (l >> 5));
            }
            #pragma unroll
            for (int nf = 0; nf < 2; ++nf) {
                int n = ns * 64 + nf * 32 + (l & 31);
                #pragma unroll
                for (int hl = 0; hl < 2; ++hl)
                    bF[nf][hl] = ldsfrag(Bt, n, hl * 4 + t2 * 2 + (l >> 5));
            }
            #pragma unroll
            for (int mf = 0; mf < 2; ++mf)
                #pragma unroll
                for (int nf = 0; nf < 2; ++nf) {
                    acc[mf][nf] = __builtin_amdgcn_mfma_f32_32x32x16_bf16(aF[mf][0], bF[nf][0], acc[mf][nf], 0, 0, 0);
                    acc[mf][nf] = __builtin_amdgcn_mfma_f32_32x32x16_bf16(aF[mf][0], bF[nf][1], acc[mf][nf], 0, 0, 0);
                    acc[mf][nf] = __builtin_amdgcn_mfma_f32_32x32x16_bf16(aF[mf][1], bF[nf][0], acc[mf][nf], 0, 0, 0);
                }
        }
        __syncthreads();
    }
    #pragma unroll
    for (int nf = 0; nf < 2; ++nf) {
        int col = ns * 64 + nf * 32 + (l & 31);
        float bb = b1[col];
        #pragma unroll
        for (int mf = 0; mf < 2; ++mf)
            #pragma unroll
            for (int r = 0; r < 16; ++r) {
                int row = mh * 64 + mf * 32 + (r & 3) + 8 * (r >> 2) + 4 * (l >> 5);
                if (n0 + row < NN) {
                    float v = silu_f(acc[mf][nf][r] + bb);
                    u[(size_t)(n0 + row) * HID + col] = f16_bits(v);
                }
            }
    }
}

// ---------------------------------------------------------------------------
// node_mlp2: upd = u @ W2u + b2u; out = lig ? LN(h+upd)*g+b : h
// ---------------------------------------------------------------------------
__global__ __launch_bounds__(512) void node_mlp2(
    const short* __restrict__ u, const short* __restrict__ w2ut,
    const float* __restrict__ b2, const float* __restrict__ h,
    const int* __restrict__ ntype, const float* __restrict__ lng,
    const float* __restrict__ lnb, float* __restrict__ out)
{
    __shared__ __align__(16) short Ah[128 * 64];
    __shared__ __align__(16) short Bh[256 * 64];
    __shared__ __align__(16) short Bl[256 * 64];
    __shared__ float red1[4][128], red2[4][128];
    __shared__ float muS[128], rsS[128];
    const int tid = threadIdx.x, l = tid & 63, w = tid >> 6;
    const int n0 = blockIdx.x * 128;
    const int mh = w >> 2, ns = w & 3;

    f32x16 acc[2][2];
    #pragma unroll
    for (int a = 0; a < 2; ++a)
        #pragma unroll
        for (int b = 0; b < 2; ++b)
            #pragma unroll
            for (int q = 0; q < 16; ++q) acc[a][b][q] = 0.0f;

    for (int c = 0; c < 4; ++c) {
        #pragma unroll
        for (int jj = 0; jj < 2; ++jj) {
            int j = w * 2 + jj;
            int row = j * 8 + (l >> 3), s = l & 7;
            int sg = s ^ (row & 7);
            int node = min(n0 + row, NN - 1);
            gll16(u + (size_t)node * HID + c * 64 + sg * 8, &Ah[j * 512]);
        }
        #pragma unroll
        for (int jj = 0; jj < 8; ++jj) {
            int j = w * 8 + jj;
            int hf = j >> 5;
            int n = (j & 31) * 8 + (l >> 3), s = l & 7;
            int sg = s ^ (n & 7);
            const short* gp = w2ut + (size_t)hf * (256*256) + n * HID + c * 64 + sg * 8;
            gll16(gp, hf ? &Bl[(j & 31) * 512] : &Bh[(j & 31) * 512]);
        }
        __syncthreads();
        #pragma unroll
        for (int t2 = 0; t2 < 4; ++t2) {
            int sg = t2 * 2 + (l >> 5);
            half8 aF[2], bH[2], bL[2];
            #pragma unroll
            for (int mf = 0; mf < 2; ++mf)
                aF[mf] = ldsfragh(Ah, mh * 64 + mf * 32 + (l & 31), sg);
            #pragma unroll
            for (int nf = 0; nf < 2; ++nf) {
                int n = ns * 64 + nf * 32 + (l & 31);
                bH[nf] = ldsfragh(Bh, n, sg);
                bL[nf] = ldsfragh(Bl, n, sg);
            }
            #pragma unroll
            for (int mf = 0; mf < 2; ++mf)
                #pragma unroll
                for (int nf = 0; nf < 2; ++nf) {
                    acc[mf][nf] = __builtin_amdgcn_mfma_f32_32x32x16_f16(aF[mf], bH[nf], acc[mf][nf], 0, 0, 0);
                    acc[mf][nf] = __builtin_amdgcn_mfma_f32_32x32x16_f16(aF[mf], bL[nf], acc[mf][nf], 0, 0, 0);
                }
        }
        __syncthreads();
    }

    // x = h + upd + b2 (into acc)
    #pragma unroll
    for (int nf = 0; nf < 2; ++nf) {
        int col = ns * 64 + nf * 32 + (l & 31);
        float bb = b2[col];
        #pragma unroll
        for (int mf = 0; mf < 2; ++mf)
            #pragma unroll
            for (int r = 0; r < 16; ++r) {
                int row = mh * 64 + mf * 32 + (r & 3) + 8 * (r >> 2) + 4 * (l >> 5);
                int node = min(n0 + row, NN - 1);
                acc[mf][nf][r] += bb + h[(size_t)node * HID + col];
            }
    }
    // per-row stats: lane partial (2 cols) -> 32-lane shuffle -> LDS cross-wave
    #pragma unroll
    for (int mf = 0; mf < 2; ++mf)
        #pragma unroll
        for (int r = 0; r < 16; ++r) {
            float v1 = acc[mf][0][r] + acc[mf][1][r];
            float v2 = acc[mf][0][r]*acc[mf][0][r] + acc[mf][1][r]*acc[mf][1][r];
            #pragma unroll
            for (int off = 16; off >= 1; off >>= 1) {
                v1 += __shfl_xor(v1, off, 64);
                v2 += __shfl_xor(v2, off, 64);
            }
            if ((l & 31) == 0) {
                int row = mh * 64 + mf * 32 + (r & 3) + 8 * (r >> 2) + 4 * (l >> 5);
                red1[ns][row] = v1; red2[ns][row] = v2;
            }
        }
    __syncthreads();
    if (tid < 128) {
        float s1 = red1[0][tid] + red1[1][tid] + red1[2][tid] + red1[3][tid];
        float s2 = red2[0][tid] + red2[1][tid] + red2[2][tid] + red2[3][tid];
        float mu = s1 * (1.0f / 256.0f);
        float var = s2 * (1.0f / 256.0f) - mu * mu;
        muS[tid] = mu;
        rsS[tid] = rsqrtf(var + 1e-5f);
    }
    __syncthreads();
    #pragma unroll
    for (int nf = 0; nf < 2; ++nf) {
        int col = ns * 64 + nf * 32 + (l & 31);
        float g = lng[col], bt = lnb[col];
        #pragma unroll
        for (int mf = 0; mf < 2; ++mf)
            #pragma unroll
            for (int r = 0; r < 16; ++r) {
                int row = mh * 64 + mf * 32 + (r & 3) + 8 * (r >> 2) + 4 * (l >> 5);
                int node = n0 + row;
                if (node < NN) {
                    float y;
                    if (ntype[node] == 1)
                        y = (acc[mf][nf][r] - muS[row]) * rsS[row] * g + bt;
                    else
                        y = h[(size_t)node * HID + col];
                    out[(size_t)node * HID + col] = y;
                }
            }
    }
}

// ===========================================================================
// fp32 fallback path (proven correct in round 1) — used if ws_size too small
// ===========================================================================
#define SWZ(k, e) ((e) ^ ((((k) >> 2) & 7) << 2))

__global__ __launch_bounds__(256) void edge_fp32(
    const float* __restrict__ h, const float* __restrict__ pos,
    const int* __restrict__ ei, const int* __restrict__ etype,
    const float* __restrict__ emb,
    const float* __restrict__ W1, const float* __restrict__ b1,
    const float* __restrict__ W2, const float* __restrict__ b2,
    float* __restrict__ seg, float* __restrict__ cnt)
{
    __shared__ float A1T[16][32];
    __shared__ float Bt[16][256];
    __shared__ float A2T[256][32];
    __shared__ float distS[32];
    __shared__ int   srcS[32], dstS[32], etS[32];
    const int tid = threadIdx.x;
    const int e0  = blockIdx.x * 32;
    if (tid < 32) {
        const int e = e0 + tid;
        const int s = ei[e];
        const int d = ei[EE + e];
        srcS[tid] = s; dstS[tid] = d; etS[tid] = etype[e];
        const float dx = pos[3*s+0] - pos[3*d+0];
        const float dy = pos[3*s+1] - pos[3*d+1];
        const float dz = pos[3*s+2] - pos[3*d+2];
        distS[tid] = sqrtf(dx*dx + dy*dy + dz*dz);
        atomicAdd(&cnt[d], 1.0f);
    }
    __syncthreads();
    const int c0 = (tid & 63) * 4;
    const int r0 = (tid >> 6) * 8;
    float acc[8][4];
    #pragma unroll
    for (int i = 0; i < 8; ++i)
        #pragma unroll
        for (int j = 0; j < 4; ++j) acc[i][j] = 0.0f;
    const float step  = 6.0f / 31.0f;
    for (int k0 = 0; k0 < 800; k0 += 16) {
        if (tid < 128) {
            const int e = tid >> 2;
            const int q = (tid & 3) * 4;
            const int k = k0 + q;
            float4 v;
            if (k < 256)       v = *(const float4*)&h[(size_t)srcS[e]*HID + k];
            else if (k < 512)  v = *(const float4*)&h[(size_t)dstS[e]*HID + (k - 256)];
            else if (k < 768)  v = *(const float4*)&emb[(size_t)etS[e]*HID + (k - 512)];
            else {
                const float de = distS[e];
                const float t0 = de - step*(float)(k-768);
                const float t1 = de - step*(float)(k-767);
                const float t2 = de - step*(float)(k-766);
                const float t3 = de - step*(float)(k-765);
                v = make_float4(__expf(-GAMMA_C*t0*t0), __expf(-GAMMA_C*t1*t1),
                                __expf(-GAMMA_C*t2*t2), __expf(-GAMMA_C*t3*t3));
            }
            A1T[q+0][e] = v.x; A1T[q+1][e] = v.y;
            A1T[q+2][e] = v.z; A1T[q+3][e] = v.w;
        }
        #pragma unroll
        for (int p = 0; p < 4; ++p) {
            const int idx = p*256 + tid;
            const int k   = idx >> 6;
            const int n   = (idx & 63) * 4;
            *(float4*)&Bt[k][n] = *(const float4*)&W1[(size_t)(k0+k)*HID + n];
        }
        __syncthreads();
        #pragma unroll
        for (int kk = 0; kk < 16; ++kk) {
            const float4 b  = *(const float4*)&Bt[kk][c0];
            const float4 a0 = *(const float4*)&A1T[kk][r0];
            const float4 a1 = *(const float4*)&A1T[kk][r0+4];
            const float a[8] = {a0.x,a0.y,a0.z,a0.w,a1.x,a1.y,a1.z,a1.w};
            #pragma unroll
            for (int i = 0; i < 8; ++i) {
                acc[i][0] = fmaf(a[i], b.x, acc[i][0]);
                acc[i][1] = fmaf(a[i], b.y, acc[i][1]);
                acc[i][2] = fmaf(a[i], b.z, acc[i][2]);
                acc[i][3] = fmaf(a[i], b.w, acc[i][3]);
            }
        }
        __syncthreads();
    }
    {
        const float4 b1v = *(const float4*)&b1[c0];
        const float bb[4] = {b1v.x, b1v.y, b1v.z, b1v.w};
        #pragma unroll
        for (int j = 0; j < 4; ++j) {
            const int k = c0 + j;
            #pragma unroll
            for (int i = 0; i < 8; ++i) {
                const float x = acc[i][j] + bb[j];
                A2T[k][SWZ(k, r0+i)] = silu_f(x);
                acc[i][j] = 0.0f;
            }
        }
    }
    __syncthreads();
    for (int k0 = 0; k0 < HID; k0 += 16) {
        #pragma unroll
        for (int p = 0; p < 4; ++p) {
            const int idx = p*256 + tid;
            const int k   = idx >> 6;
            const int n   = (idx & 63) * 4;
            *(float4*)&Bt[k][n] = *(const float4*)&W2[(size_t)(k0+k)*HID + n];
        }
        __syncthreads();
        #pragma unroll
        for (int kk = 0; kk < 16; ++kk) {
            const int K = k0 + kk;
            const float4 b  = *(const float4*)&Bt[kk][c0];
            const float4 a0 = *(const float4*)&A2T[K][SWZ(K, r0)];
            const float4 a1 = *(const float4*)&A2T[K][SWZ(K, r0+4)];
            const float a[8] = {a0.x,a0.y,a0.z,a0.w,a1.x,a1.y,a1.z,a1.w};
            #pragma unroll
            for (int i = 0; i < 8; ++i) {
                acc[i][0] = fmaf(a[i], b.x, acc[i][0]);
                acc[i][1] = fmaf(a[i], b.y, acc[i][1]);
                acc[i][2] = fmaf(a[i], b.z, acc[i][2]);
                acc[i][3] = fmaf(a[i], b.w, acc[i][3]);
            }
        }
        __syncthreads();
    }
    {
        const float4 b2v = *(const float4*)&b2[c0];
        const float bb[4] = {b2v.x, b2v.y, b2v.z, b2v.w};
        #pragma unroll
        for (int i = 0; i < 8; ++i) {
            const int d = dstS[r0 + i];
            float* outp = &seg[(size_t)d*HID + c0];
            #pragma unroll
            for (int j = 0; j < 4; ++j) {
                const float x = acc[i][j] + bb[j];
                atomicAdd(&outp[j], silu_f(x));
            }
        }
    }
}

__global__ __launch_bounds__(256) void node_fp32(
    const float* __restrict__ h, const float* __restrict__ seg,
    const float* __restrict__ cnt, const int* __restrict__ ntype,
    const float* __restrict__ W1, const float* __restrict__ b1,
    const float* __restrict__ W2, const float* __restrict__ b2,
    const float* __restrict__ lng, const float* __restrict__ lnb,
    float* __restrict__ out)
{
    __shared__ float A1T[16][32];
    __shared__ float Bt[16][256];
    __shared__ float A2T[256][32];
    __shared__ float invS[32];
    const int tid = threadIdx.x;
    const int n0  = blockIdx.x * 32;
    if (tid < 32) invS[tid] = 1.0f / fmaxf(cnt[n0 + tid], 1.0f);
    __syncthreads();
    const int c0 = (tid & 63) * 4;
    const int r0 = (tid >> 6) * 8;
    float acc[8][4];
    #pragma unroll
    for (int i = 0; i < 8; ++i)
        #pragma unroll
        for (int j = 0; j < 4; ++j) acc[i][j] = 0.0f;
    for (int k0 = 0; k0 < 512; k0 += 16) {
        if (tid < 128) {
            const int e = tid >> 2;
            const int q = (tid & 3) * 4;
            const int k = k0 + q;
            float4 v;
            if (k < 256) v = *(const float4*)&h[(size_t)(n0+e)*HID + k];
            else {
                v = *(const float4*)&seg[(size_t)(n0+e)*HID + (k - 256)];
                const float ic = invS[e];
                v.x *= ic; v.y *= ic; v.z *= ic; v.w *= ic;
            }
            A1T[q+0][e] = v.x; A1T[q+1][e] = v.y;
            A1T[q+2][e] = v.z; A1T[q+3][e] = v.w;
        }
        #pragma unroll
        for (int p = 0; p < 4; ++p) {
            const int idx = p*256 + tid;
            const int k   = idx >> 6;
            const int n   = (idx & 63) * 4;
            *(float4*)&Bt[k][n] = *(const float4*)&W1[(size_t)(k0+k)*HID + n];
        }
        __syncthreads();
        #pragma unroll
        for (int kk = 0; kk < 16; ++kk) {
            const float4 b  = *(const float4*)&Bt[kk][c0];
            const float4 a0 = *(const float4*)&A1T[kk][r0];
            const float4 a1 = *(const float4*)&A1T[kk][r0+4];
            const float a[8] = {a0.x,a0.y,a0.z,a0.w,a1.x,a1.y,a1.z,a1.w};
            #pragma unroll
            for (int i = 0; i < 8; ++i) {
                acc[i][0] = fmaf(a[i], b.x, acc[i][0]);
                acc[i][1] = fmaf(a[i], b.y, acc[i][1]);
                acc[i][2] = fmaf(a[i], b.z, acc[i][2]);
                acc[i][3] = fmaf(a[i], b.w, acc[i][3]);
            }
        }
        __syncthreads();
    }
    {
        const float4 b1v = *(const float4*)&b1[c0];
        const float bb[4] = {b1v.x, b1v.y, b1v.z, b1v.w};
        #pragma unroll
        for (int j = 0; j < 4; ++j) {
            const int k = c0 + j;
            #pragma unroll
            for (int i = 0; i < 8; ++i) {
                const float x = acc[i][j] + bb[j];
                A2T[k][SWZ(k, r0+i)] = silu_f(x);
                acc[i][j] = 0.0f;
            }
        }
    }
    __syncthreads();
    for (int k0 = 0; k0 < HID; k0 += 16) {
        #pragma unroll
        for (int p = 0; p < 4; ++p) {
            const int idx = p*256 + tid;
            const int k   = idx >> 6;
            const int n   = (idx & 63) * 4;
            *(float4*)&Bt[k][n] = *(const float4*)&W2[(size_t)(k0+k)*HID + n];
        }
        __syncthreads();
        #pragma unroll
        for (int kk = 0; kk < 16; ++kk) {
            const int K = k0 + kk;
            const float4 b  = *(const float4*)&Bt[kk][c0];
            const float4 a0 = *(const float4*)&A2T[K][SWZ(K, r0)];
            const float4 a1 = *(const float4*)&A2T[K][SWZ(K, r0+4)];
            const float a[8] = {a0.x,a0.y,a0.z,a0.w,a1.x,a1.y,a1.z,a1.w};
            #pragma unroll
            for (int i = 0; i < 8; ++i) {
                acc[i][0] = fmaf(a[i], b.x, acc[i][0]);
                acc[i][1] = fmaf(a[i], b.y, acc[i][1]);
                acc[i][2] = fmaf(a[i], b.z, acc[i][2]);
                acc[i][3] = fmaf(a[i], b.w, acc[i][3]);
            }
        }
        __syncthreads();
    }
    {
        const float4 b2v = *(const float4*)&b2[c0];
        const float bb[4] = {b2v.x, b2v.y, b2v.z, b2v.w};
        float4 hv[8];
        #pragma unroll
        for (int i = 0; i < 8; ++i) {
            hv[i] = *(const float4*)&h[(size_t)(n0+r0+i)*HID + c0];
            acc[i][0] = hv[i].x + acc[i][0] + bb[0];
            acc[i][1] = hv[i].y + acc[i][1] + bb[1];
            acc[i][2] = hv[i].z + acc[i][2] + bb[2];
            acc[i][3] = hv[i].w + acc[i][3] + bb[3];
        }
        float s1[8], s2[8];
        #pragma unroll
        for (int i = 0; i < 8; ++i) {
            s1[i] = acc[i][0] + acc[i][1] + acc[i][2] + acc[i][3];
            s2[i] = acc[i][0]*acc[i][0] + acc[i][1]*acc[i][1]
                  + acc[i][2]*acc[i][2] + acc[i][3]*acc[i][3];
        }
        #pragma unroll
        for (int off = 32; off >= 1; off >>= 1) {
            #pragma unroll
            for (int i = 0; i < 8; ++i) {
                s1[i] += __shfl_xor(s1[i], off, 64);
                s2[i] += __shfl_xor(s2[i], off, 64);
            }
        }
        const float4 gv = *(const float4*)&lng[c0];
        const float4 bv = *(const float4*)&lnb[c0];
        const float g[4] = {gv.x, gv.y, gv.z, gv.w};
        const float bb2[4] = {bv.x, bv.y, bv.z, bv.w};
        #pragma unroll
        for (int i = 0; i < 8; ++i) {
            const int n = n0 + r0 + i;
            const bool lig = (ntype[n] == 1);
            float4 y;
            if (lig) {
                const float mu  = s1[i] * (1.0f/256.0f);
                const float var = s2[i] * (1.0f/256.0f) - mu*mu;
                const float rs  = rsqrtf(var + 1e-5f);
                y.x = (acc[i][0] - mu) * rs * g[0] + bb2[0];
                y.y = (acc[i][1] - mu) * rs * g[1] + bb2[1];
                y.z = (acc[i][2] - mu) * rs * g[2] + bb2[2];
                y.w = (acc[i][3] - mu) * rs * g[3] + bb2[3];
            } else {
                y = hv[i];
            }
            *(float4*)&out[(size_t)n*HID + c0] = y;
        }
    }
}

// ===========================================================================
extern "C" void kernel_launch(void* const* d_in, const int* in_sizes, int n_in,
                              void* d_out, int out_size, void* d_ws, size_t ws_size,
                              hipStream_t stream) {
    (void)in_sizes; (void)n_in; (void)out_size;
    const float* h    = (const float*)d_in[0];
    const float* pos  = (const float*)d_in[1];
    const int*   ei   = (const int*)  d_in[2];
    const int*   et   = (const int*)  d_in[3];
    const int*   nt   = (const int*)  d_in[4];
    const float* emb  = (const float*)d_in[5];
    const float* W1m  = (const float*)d_in[6];
    const float* b1m  = (const float*)d_in[7];
    const float* W2m  = (const float*)d_in[8];
    const float* b2m  = (const float*)d_in[9];
    const float* W1u  = (const float*)d_in[10];
    const float* b1u  = (const float*)d_in[11];
    const float* W2u  = (const float*)d_in[12];
    const float* b2u  = (const float*)d_in[13];
    const float* lng  = (const float*)d_in[14];
    const float* lnb  = (const float*)d_in[15];
    float* out = (float*)d_out;

    // workspace layout (512B-aligned segments)
    size_t o = 0;
    auto al = [&](size_t b) { size_t r = o; o = (o + b + 511) & ~(size_t)511; return r; };
    const size_t o_seg  = al((size_t)NN * HID * 4);
    const size_t o_cnt  = al((size_t)NN * 4);
    const size_t o_zend = o;                       // memset range [0, o_zend)
    const size_t o_hpl  = al((size_t)2 * NN * HID * 2);
    const size_t o_emb  = al((size_t)2 * 2 * HID * 2);
    const size_t o_w1t  = al((size_t)2 * 256 * 800 * 2);
    const size_t o_w2t  = al((size_t)2 * 256 * 256 * 2);
    const size_t o_w1ut = al((size_t)2 * 256 * 512 * 2);
    const size_t o_w2ut = al((size_t)2 * 256 * 256 * 2);
    const size_t o_mipl = al((size_t)2 * NN * HID * 2);
    const size_t o_upl  = al((size_t)NN * HID * 2);
    const size_t o_mhi  = al((size_t)EE * HID * 2);
    const size_t need = o;

    char* ws = (char*)d_ws;
    float* seg = (float*)(ws + o_seg);
    float* cnt = (float*)(ws + o_cnt);

    if (ws_size >= need) {
        short* hpl   = (short*)(ws + o_hpl);
        short* embpl = (short*)(ws + o_emb);
        short* w1t   = (short*)(ws + o_w1t);
        short* w2t   = (short*)(ws + o_w2t);
        short* w1ut  = (short*)(ws + o_w1ut);
        short* w2ut  = (short*)(ws + o_w2ut);
        short* mipl  = (short*)(ws + o_mipl);
        short* upl   = (short*)(ws + o_upl);
        short* mhi   = (short*)(ws + o_mhi);

        hipMemsetAsync(d_ws, 0, o_zend, stream);
        prep_all<<<PREP_TOTAL / 256, 256, 0, stream>>>(
            h, emb, W1m, W2m, W1u, W2u, hpl, embpl, w1t, w2t, w1ut, w2ut);
        edge_mlp1<<<EE / 128, 512, 0, stream>>>(
            hpl, embpl, w1t, b1m, pos, ei, et, mhi, cnt);
        edge_mlp2<<<EE / 128, 512, 0, stream>>>(mhi, w2t, b2m, ei, seg);
        mi_prep<<<(NN * HID) / 256, 256, 0, stream>>>(seg, cnt, mipl);
        const int nb = (NN + 127) / 128;
        node_mlp1<<<nb, 512, 0, stream>>>(hpl, mipl, w1ut, b1u, upl);
        node_mlp2<<<nb, 512, 0, stream>>>(upl, w2ut, b2u, h, nt, lng, lnb, out);
    } else {
        // fp32 fallback (round-1 kernels)
        hipMemsetAsync(d_ws, 0, ((size_t)NN * HID + NN) * sizeof(float), stream);
        float* seg0 = (float*)d_ws;
        float* cnt0 = seg0 + (size_t)NN * HID;
        edge_fp32<<<EE / 32, 256, 0, stream>>>(h, pos, ei, et, emb,
                                               W1m, b1m, W2m, b2m, seg0, cnt0);
        node_fp32<<<NN / 32, 256, 0, stream>>>(h, seg0, cnt0, nt,
                                               W1u, b1u, W2u, b2u, lng, lnb, out);
    }
}

// Round 4
// 935.820 us; speedup vs baseline: 3.2013x; 1.0848x over previous
//
#include <hip/hip_runtime.h>
#include <hip/hip_fp16.h>
#include <math.h>

#define NN   20000
#define EE   320000
#define HID  256
#define GAMMA_C ((31.0f/6.0f)*(31.0f/6.0f))   // 1/step^2, step = 6/31

typedef __attribute__((ext_vector_type(8)))  short    short8;   // 8 bf16 bits
typedef __attribute__((ext_vector_type(8)))  _Float16 half8;    // 8 fp16
typedef __attribute__((ext_vector_type(16))) float    f32x16;

__device__ __forceinline__ float silu_f(float x) {
    return x / (1.0f + __expf(-x));
}

// fp32 -> bf16 RNE bits
__device__ __forceinline__ short bf_hi(float x) {
    unsigned u = __float_as_uint(x);
    return (short)((u + 0x7fffu + ((u >> 16) & 1u)) >> 16);
}
__device__ __forceinline__ float bf_tof(short b) {
    return __uint_as_float(((unsigned)(unsigned short)b) << 16);
}
__device__ __forceinline__ void cvt_bf16_pair(float x, short* hi, short* lo) {
    short h = bf_hi(x);
    *hi = h;
    *lo = bf_hi(x - bf_tof(h));
}
__device__ __forceinline__ void cvt_f16_pair(float x, short* hi, short* lo) {
    __half h = __float2half_rn(x);
    *hi = (short)__half_as_ushort(h);
    *lo = (short)__half_as_ushort(__float2half_rn(x - __half2float(h)));
}
__device__ __forceinline__ short f16_bits(float x) {
    return (short)__half_as_ushort(__float2half_rn(x));
}

// async global->LDS, 16B per lane; LDS dest = uniform base + lane*16
typedef __attribute__((address_space(1))) const void GV;
typedef __attribute__((address_space(3))) void LV;
__device__ __forceinline__ void gll16(const void* g, void* l) {
    __builtin_amdgcn_global_load_lds((GV*)g, (LV*)l, 16, 0, 0);
}

// 128B rows = 8 slots of 16B; physical slot = sg ^ (row&7) (involution on
// both stage-source and read side — rule #21).
__device__ __forceinline__ short8 ldsfrag(const short* t, int row, int sg) {
    int s = sg ^ (row & 7);
    return *(const short8*)&t[row * 64 + s * 8];
}
// 64B rows = 4 slots of 16B; slot = sg ^ (row&3)
__device__ __forceinline__ half8 ldsfragh32(const short* t, int row, int sg) {
    int s = sg ^ (row & 3);
    return *(const half8*)&t[row * 32 + s * 8];
}
__device__ __forceinline__ short8 ldsfrag32(const short* t, int row, int sg) {
    int s = sg ^ (row & 3);
    return *(const short8*)&t[row * 32 + s * 8];
}
__device__ __forceinline__ half8 ldsfragh(const short* t, int row, int sg) {
    int s = sg ^ (row & 7);
    return *(const half8*)&t[row * 64 + s * 8];
}

// ---------------------------------------------------------------------------
// prep: fp32 -> split planes.  bf16 pairs: h, emb, W1m^T, W1u^T.
//       f16 pairs: W2m^T, W2u^T (feed the f16 GEMM2s).
// ---------------------------------------------------------------------------
#define S0 (NN*HID)     // h        5,120,000
#define S1 (2*HID)      // emb      512
#define S2 (256*800)    // W1t      204,800
#define S3 (256*256)    // W2t      65,536
#define S4 (256*512)    // W1ut     131,072
#define S5 (256*256)    // W2ut     65,536
#define PREP_TOTAL (S0+S1+S2+S3+S4+S5)   // 5,587,456 = 21826*256

__global__ __launch_bounds__(256) void prep_all(
    const float* __restrict__ h, const float* __restrict__ emb,
    const float* __restrict__ W1m, const float* __restrict__ W2m,
    const float* __restrict__ W1u, const float* __restrict__ W2u,
    short* __restrict__ hpl, short* __restrict__ embpl,
    short* __restrict__ w1t, short* __restrict__ w2t,
    short* __restrict__ w1ut, short* __restrict__ w2ut)
{
    int i = blockIdx.x * 256 + threadIdx.x;
    float x; short *hi, *lo; int o; int f16 = 0;
    if (i < S0)              { x = h[i];   hi = hpl;   lo = hpl + S0;   o = i; }
    else if ((i -= S0) < S1) { x = emb[i]; hi = embpl; lo = embpl + S1; o = i; }
    else if ((i -= S1) < S2) { int n = i / 800, k = i - n * 800;
                               x = W1m[k * 256 + n]; hi = w1t; lo = w1t + S2; o = i; }
    else if ((i -= S2) < S3) { int n = i >> 8, k = i & 255;
                               x = W2m[k * 256 + n]; hi = w2t; lo = w2t + S3; o = i; f16 = 1; }
    else if ((i -= S3) < S4) { int n = i >> 9, k = i & 511;
                               x = W1u[k * 256 + n]; hi = w1ut; lo = w1ut + S4; o = i; }
    else if ((i -= S4) < S5) { int n = i >> 8, k = i & 255;
                               x = W2u[k * 256 + n]; hi = w2ut; lo = w2ut + S5; o = i; f16 = 1; }
    else return;
    short hb, lb;
    if (f16) cvt_f16_pair(x, &hb, &lb); else cvt_bf16_pair(x, &hb, &lb);
    hi[o] = hb; lo[o] = lb;
}

// ---------------------------------------------------------------------------
// edge_mlp1 v2: m = silu(m_in @ W1m + b1m) -> fp16 plane.
// Block = 128 edges x 128 cols (grid.y = 2 col-blocks). 512 thr, 8 waves
// (2 row-halves x 4 col-stripes), wave tile 64x32 -> acc 32 AGPR.
// launch_bounds(512,4): cap unified regs at 128 -> 2 blocks/CU.
// Double-buffered A+B with stage-ahead (2-phase T3 recipe): stage chunk c+1
// BEFORE computing chunk c; __syncthreads' implicit vmcnt(0) lands it.
// K=800 in 25 chunks of 32; 3-term split bf16 (hi*hi + hi*lo + lo*hi).
// ---------------------------------------------------------------------------
__global__ __launch_bounds__(512, 4) void edge_mlp1(
    const short* __restrict__ hpl, const short* __restrict__ embpl,
    const short* __restrict__ w1t, const float* __restrict__ b1,
    const float* __restrict__ pos, const int* __restrict__ ei,
    const int* __restrict__ etype,
    short* __restrict__ mhi, float* __restrict__ cnt)
{
    __shared__ __align__(16) short At[2][128 * 64];   // 2 x 16 KB
    __shared__ __align__(16) short Bt[2][128 * 64];   // 2 x 16 KB
    __shared__ int srcS[128], dstS[128], etS[128];
    __shared__ float distS[128];

    const int tid = threadIdx.x, l = tid & 63, w = tid >> 6;
    const int e0 = blockIdx.x * 128;
    const int cb = blockIdx.y;                 // col-block: cols cb*128..+127
    const int mh = w >> 2, ns = w & 3;

    if (tid < 128) {
        int s = ei[e0 + tid], d = ei[EE + e0 + tid];
        srcS[tid] = s; dstS[tid] = d; etS[tid] = etype[e0 + tid];
        float dx = pos[3*s]   - pos[3*d];
        float dy = pos[3*s+1] - pos[3*d+1];
        float dz = pos[3*s+2] - pos[3*d+2];
        distS[tid] = sqrtf(dx*dx + dy*dy + dz*dz);
        if (cb == 0) atomicAdd(&cnt[d], 1.0f);
    }
    __syncthreads();

    // ---- staging lambdas ----
    auto stageA = [&](int buf, int c) {
        if (c < 24) {
            #pragma unroll
            for (int jj = 0; jj < 2; ++jj) {
                int j = w * 2 + jj;
                int row = j * 8 + (l >> 3), s = l & 7;
                int sg = s ^ (row & 7);
                int hl = sg >> 2, q = sg & 3;
                const short* gp;
                if (c < 8)
                    gp = hpl + (size_t)hl * (NN*HID) + (size_t)srcS[row] * HID + c*32 + q*8;
                else if (c < 16)
                    gp = hpl + (size_t)hl * (NN*HID) + (size_t)dstS[row] * HID + (c-8)*32 + q*8;
                else
                    gp = embpl + hl * (2*HID) + etS[row] * HID + (c-16)*32 + q*8;
                gll16(gp, &At[buf][j * 512]);
            }
        } else {
            // RBF chunk (k 768..799): compute + swizzled ds_write
            #pragma unroll
            for (int jj = 0; jj < 2; ++jj) {
                int it = tid * 2 + jj;
                int row = it >> 3, s = it & 7;
                int sg = s ^ (row & 7);
                int hl = sg >> 2, q = sg & 3;
                float d = distS[row];
                short8 v;
                #pragma unroll
                for (int k8 = 0; k8 < 8; ++k8) {
                    float cen = (float)(q * 8 + k8) * (6.0f / 31.0f);
                    float t = d - cen;
                    float f = __expf(-GAMMA_C * t * t);
                    short hb = bf_hi(f);
                    v[k8] = hl ? bf_hi(f - bf_tof(hb)) : hb;
                }
                *(short8*)&At[buf][row * 64 + s * 8] = v;
            }
        }
    };
    auto stageB = [&](int buf, int c) {
        #pragma unroll
        for (int jj = 0; jj < 2; ++jj) {
            int j = w * 2 + jj;
            int n = j * 8 + (l >> 3), s = l & 7;
            int sg = s ^ (n & 7);
            int hl = sg >> 2, q = sg & 3;
            const short* gp = w1t + (size_t)hl * (256*800)
                            + (size_t)(cb*128 + n) * 800 + c*32 + q*8;
            gll16(gp, &Bt[buf][j * 512]);
        }
    };

    f32x16 acc[2];
    #pragma unroll
    for (int a = 0; a < 2; ++a)
        #pragma unroll
        for (int q = 0; q < 16; ++q) acc[a][q] = 0.0f;

    // prologue: stage chunk 0
    stageA(0, 0); stageB(0, 0);
    __syncthreads();

    int cur = 0;
    for (int c = 0; c < 25; ++c) {
        if (c < 24) { stageA(cur ^ 1, c + 1); stageB(cur ^ 1, c + 1); }
        #pragma unroll
        for (int t2 = 0; t2 < 2; ++t2) {
            short8 aF[2][2], bF[2];
            #pragma unroll
            for (int mf = 0; mf < 2; ++mf) {
                int row = mh * 64 + mf * 32 + (l & 31);
                #pragma unroll
                for (int hl = 0; hl < 2; ++hl)
                    aF[mf][hl] = ldsfrag(&At[cur][0], row, hl * 4 + t2 * 2 + (l >> 5));
            }
            {
                int n = ns * 32 + (l & 31);
                #pragma unroll
                for (int hl = 0; hl < 2; ++hl)
                    bF[hl] = ldsfrag(&Bt[cur][0], n, hl * 4 + t2 * 2 + (l >> 5));
            }
            #pragma unroll
            for (int mf = 0; mf < 2; ++mf) {
                acc[mf] = __builtin_amdgcn_mfma_f32_32x32x16_bf16(aF[mf][0], bF[0], acc[mf], 0, 0, 0);
                acc[mf] = __builtin_amdgcn_mfma_f32_32x32x16_bf16(aF[mf][0], bF[1], acc[mf], 0, 0, 0);
                acc[mf] = __builtin_amdgcn_mfma_f32_32x32x16_bf16(aF[mf][1], bF[0], acc[mf], 0, 0, 0);
            }
        }
        __syncthreads();   // drains vmcnt (c+1 stage landed) + lgkm; swap
        cur ^= 1;
    }

    // epilogue: bias + silu -> fp16 m plane
    {
        int col = cb * 128 + ns * 32 + (l & 31);
        float bb = b1[col];
        #pragma unroll
        for (int mf = 0; mf < 2; ++mf)
            #pragma unroll
            for (int r = 0; r < 16; ++r) {
                int row = mh * 64 + mf * 32 + (r & 3) + 8 * (r >> 2) + 4 * (l >> 5);
                float v = silu_f(acc[mf][r] + bb);
                mhi[(size_t)(e0 + row) * HID + col] = f16_bits(v);
            }
    }
}

// ---------------------------------------------------------------------------
// edge_mlp2 v2: m_ij = silu(m @ W2m + b2m); atomicAdd into seg[dst].
// Same 128x128 / wave-64x32 / dbuf / stage-ahead structure.
// A = fp16 m (single), B = fp16 W2^T hi/lo (2-term). K=256, 8 chunks of 32.
// 64B LDS rows -> 4-slot swizzle.
// ---------------------------------------------------------------------------
__global__ __launch_bounds__(512, 4) void edge_mlp2(
    const short* __restrict__ mhi, const short* __restrict__ w2t,
    const float* __restrict__ b2, const int* __restrict__ ei,
    float* __restrict__ seg)
{
    __shared__ __align__(16) short Ah[2][128 * 32];   // 2 x 8 KB
    __shared__ __align__(16) short Bh[2][128 * 32];
    __shared__ __align__(16) short Bl[2][128 * 32];
    __shared__ int dstS[128];
    const int tid = threadIdx.x, l = tid & 63, w = tid >> 6;
    const int e0 = blockIdx.x * 128;
    const int cb = blockIdx.y;
    const int mh = w >> 2, ns = w & 3;
    if (tid < 128) dstS[tid] = ei[EE + e0 + tid];
    __syncthreads();

    auto stageA = [&](int buf, int c) {
        // 8 gll16 total -> 1 per wave; each covers 16 rows of 64B
        int row = w * 16 + (l >> 2), s = l & 3;
        int sg = s ^ (row & 3);
        gll16(mhi + (size_t)(e0 + row) * HID + c * 32 + sg * 8, &Ah[buf][w * 512]);
    };
    auto stageB = [&](int buf, int c) {
        #pragma unroll
        for (int jj = 0; jj < 2; ++jj) {
            int j = w * 2 + jj;          // 0..15
            int hf = j >> 3, jn = j & 7;
            int n = jn * 16 + (l >> 2), s = l & 3;
            int sg = s ^ (n & 3);
            const short* gp = w2t + (size_t)hf * (256*256)
                            + (size_t)(cb*128 + n) * HID + c * 32 + sg * 8;
            gll16(gp, hf ? &Bl[buf][jn * 512] : &Bh[buf][jn * 512]);
        }
    };

    f32x16 acc[2];
    #pragma unroll
    for (int a = 0; a < 2; ++a)
        #pragma unroll
        for (int q = 0; q < 16; ++q) acc[a][q] = 0.0f;

    stageA(0, 0); stageB(0, 0);
    __syncthreads();

    int cur = 0;
    for (int c = 0; c < 8; ++c) {
        if (c < 7) { stageA(cur ^ 1, c + 1); stageB(cur ^ 1, c + 1); }
        #pragma unroll
        for (int t2 = 0; t2 < 2; ++t2) {
            int sg = t2 * 2 + (l >> 5);
            half8 aF[2], bH, bL;
            #pragma unroll
            for (int mf = 0; mf < 2; ++mf)
                aF[mf] = ldsfragh32(&Ah[cur][0], mh * 64 + mf * 32 + (l & 31), sg);
            {
                int n = ns * 32 + (l & 31);
                bH = ldsfragh32(&Bh[cur][0], n, sg);
                bL = ldsfragh32(&Bl[cur][0], n, sg);
            }
            #pragma unroll
            for (int mf = 0; mf < 2; ++mf) {
                acc[mf] = __builtin_amdgcn_mfma_f32_32x32x16_f16(aF[mf], bH, acc[mf], 0, 0, 0);
                acc[mf] = __builtin_amdgcn_mfma_f32_32x32x16_f16(aF[mf], bL, acc[mf], 0, 0, 0);
            }
        }
        __syncthreads();
        cur ^= 1;
    }

    {
        int col = cb * 128 + ns * 32 + (l & 31);
        float bb = b2[col];
        #pragma unroll
        for (int mf = 0; mf < 2; ++mf)
            #pragma unroll
            for (int r = 0; r < 16; ++r) {
                int row = mh * 64 + mf * 32 + (r & 3) + 8 * (r >> 2) + 4 * (l >> 5);
                float v = silu_f(acc[mf][r] + bb);
                atomicAdd(&seg[(size_t)dstS[row] * HID + col], v);
            }
    }
}

// ---------------------------------------------------------------------------
// mi_prep: m_i = seg / max(cnt,1) -> bf16 hi/lo planes
// ---------------------------------------------------------------------------
__global__ __launch_bounds__(256) void mi_prep(
    const float* __restrict__ seg, const float* __restrict__ cnt,
    short* __restrict__ mipl)
{
    int i = blockIdx.x * 256 + threadIdx.x;
    int row = i >> 8;
    float v = seg[i] / fmaxf(cnt[row], 1.0f);
    short hb, lb;
    cvt_bf16_pair(v, &hb, &lb);
    mipl[i] = hb;
    mipl[(size_t)NN * HID + i] = lb;
}

// ---------------------------------------------------------------------------
// node_mlp1: u = silu([h, m_i] @ W1u + b1u) -> fp16 plane. K=512, 16 chunks.
// (round-3 passing version, unchanged)
// ---------------------------------------------------------------------------
__global__ __launch_bounds__(512) void node_mlp1(
    const short* __restrict__ hpl, const short* __restrict__ mipl,
    const short* __restrict__ w1ut, const float* __restrict__ b1,
    short* __restrict__ u)
{
    __shared__ __align__(16) short At[128 * 64];
    __shared__ __align__(16) short Bt[256 * 64];
    const int tid = threadIdx.x, l = tid & 63, w = tid >> 6;
    const int n0 = blockIdx.x * 128;
    const int mh = w >> 2, ns = w & 3;

    f32x16 acc[2][2];
    #pragma unroll
    for (int a = 0; a < 2; ++a)
        #pragma unroll
        for (int b = 0; b < 2; ++b)
            #pragma unroll
            for (int q = 0; q < 16; ++q) acc[a][b][q] = 0.0f;

    for (int c = 0; c < 16; ++c) {
        #pragma unroll
        for (int jj = 0; jj < 2; ++jj) {
            int j = w * 2 + jj;
            int row = j * 8 + (l >> 3), s = l & 7;
            int sg = s ^ (row & 7);
            int hl = sg >> 2, q = sg & 3;
            int node = min(n0 + row, NN - 1);
            const short* gp = (c < 8)
                ? hpl  + (size_t)hl * (NN*HID) + (size_t)node * HID + c * 32 + q * 8
                : mipl + (size_t)hl * (NN*HID) + (size_t)node * HID + (c - 8) * 32 + q * 8;
            gll16(gp, &At[j * 512]);
        }
        #pragma unroll
        for (int jj = 0; jj < 4; ++jj) {
            int j = w * 4 + jj;
            int n = j * 8 + (l >> 3), s = l & 7;
            int sg = s ^ (n & 7);
            int hl = sg >> 2, q = sg & 3;
            const short* gp = w1ut + (size_t)hl * (256*512) + n * 512 + c * 32 + q * 8;
            gll16(gp, &Bt[j * 512]);
        }
        __syncthreads();
        #pragma unroll
        for (int t2 = 0; t2 < 2; ++t2) {
            short8 aF[2][2], bF[2][2];
            #pragma unroll
            for (int mf = 0; mf < 2; ++mf) {
                int row = mh * 64 + mf * 32 + (l & 31);
                #pragma unroll
                for (int hl = 0; hl < 2; ++hl)
                    aF[mf][hl] = ldsfrag(At, row, hl * 4 + t2 * 2 + (l >> 5));
            }
            #pragma unroll
            for (int nf = 0; nf < 2; ++nf) {
                int n = ns * 64 + nf * 32 + (l & 31);
                #pragma unroll
                for (int hl = 0; hl < 2; ++hl)
                    bF[nf][hl] = ldsfrag(Bt, n, hl * 4 + t2 * 2 + (l >> 5));
            }
            #pragma unroll
            for (int mf = 0; mf < 2; ++mf)
                #pragma unroll
                for (int nf = 0; nf < 2; ++nf) {
                    acc[mf][nf] = __builtin_amdgcn_mfma_f32_32x32x16_bf16(aF[mf][0], bF[nf][0], acc[mf][nf], 0, 0, 0);
                    acc[mf][nf] = __builtin_amdgcn_mfma_f32_32x32x16_bf16(aF[mf][0], bF[nf][1], acc[mf][nf], 0, 0, 0);
                    acc[mf][nf] = __builtin_amdgcn_mfma_f32_32x32x16_bf16(aF[mf][1], bF[nf][0], acc[mf][nf], 0, 0, 0);
                }
        }
        __syncthreads();
    }
    #pragma unroll
    for (int nf = 0; nf < 2; ++nf) {
        int col = ns * 64 + nf * 32 + (l & 31);
        float bb = b1[col];
        #pragma unroll
        for (int mf = 0; mf < 2; ++mf)
            #pragma unroll
            for (int r = 0; r < 16; ++r) {
                int row = mh * 64 + mf * 32 + (r & 3) + 8 * (r >> 2) + 4 * (l >> 5);
                if (n0 + row < NN) {
                    float v = silu_f(acc[mf][nf][r] + bb);
                    u[(size_t)(n0 + row) * HID + col] = f16_bits(v);
                }
            }
    }
}

// ---------------------------------------------------------------------------
// node_mlp2: upd = u @ W2u + b2u; out = lig ? LN(h+upd)*g+b : h
// (round-3 passing version, unchanged)
// ---------------------------------------------------------------------------
__global__ __launch_bounds__(512) void node_mlp2(
    const short* __restrict__ u, const short* __restrict__ w2ut,
    const float* __restrict__ b2, const float* __restrict__ h,
    const int* __restrict__ ntype, const float* __restrict__ lng,
    const float* __restrict__ lnb, float* __restrict__ out)
{
    __shared__ __align__(16) short Ah[128 * 64];
    __shared__ __align__(16) short Bh[256 * 64];
    __shared__ __align__(16) short Bl[256 * 64];
    __shared__ float red1[4][128], red2[4][128];
    __shared__ float muS[128], rsS[128];
    const int tid = threadIdx.x, l = tid & 63, w = tid >> 6;
    const int n0 = blockIdx.x * 128;
    const int mh = w >> 2, ns = w & 3;

    f32x16 acc[2][2];
    #pragma unroll
    for (int a = 0; a < 2; ++a)
        #pragma unroll
        for (int b = 0; b < 2; ++b)
            #pragma unroll
            for (int q = 0; q < 16; ++q) acc[a][b][q] = 0.0f;

    for (int c = 0; c < 4; ++c) {
        #pragma unroll
        for (int jj = 0; jj < 2; ++jj) {
            int j = w * 2 + jj;
            int row = j * 8 + (l >> 3), s = l & 7;
            int sg = s ^ (row & 7);
            int node = min(n0 + row, NN - 1);
            gll16(u + (size_t)node * HID + c * 64 + sg * 8, &Ah[j * 512]);
        }
        #pragma unroll
        for (int jj = 0; jj < 8; ++jj) {
            int j = w * 8 + jj;
            int hf = j >> 5;
            int n = (j & 31) * 8 + (l >> 3), s = l & 7;
            int sg = s ^ (n & 7);
            const short* gp = w2ut + (size_t)hf * (256*256) + n * HID + c * 64 + sg * 8;
            gll16(gp, hf ? &Bl[(j & 31) * 512] : &Bh[(j & 31) * 512]);
        }
        __syncthreads();
        #pragma unroll
        for (int t2 = 0; t2 < 4; ++t2) {
            int sg = t2 * 2 + (l >> 5);
            half8 aF[2], bH[2], bL[2];
            #pragma unroll
            for (int mf = 0; mf < 2; ++mf)
                aF[mf] = ldsfragh(Ah, mh * 64 + mf * 32 + (l & 31), sg);
            #pragma unroll
            for (int nf = 0; nf < 2; ++nf) {
                int n = ns * 64 + nf * 32 + (l & 31);
                bH[nf] = ldsfragh(Bh, n, sg);
                bL[nf] = ldsfragh(Bl, n, sg);
            }
            #pragma unroll
            for (int mf = 0; mf < 2; ++mf)
                #pragma unroll
                for (int nf = 0; nf < 2; ++nf) {
                    acc[mf][nf] = __builtin_amdgcn_mfma_f32_32x32x16_f16(aF[mf], bH[nf], acc[mf][nf], 0, 0, 0);
                    acc[mf][nf] = __builtin_amdgcn_mfma_f32_32x32x16_f16(aF[mf], bL[nf], acc[mf][nf], 0, 0, 0);
                }
        }
        __syncthreads();
    }

    // x = h + upd + b2 (into acc)
    #pragma unroll
    for (int nf = 0; nf < 2; ++nf) {
        int col = ns * 64 + nf * 32 + (l & 31);
        float bb = b2[col];
        #pragma unroll
        for (int mf = 0; mf < 2; ++mf)
            #pragma unroll
            for (int r = 0; r < 16; ++r) {
                int row = mh * 64 + mf * 32 + (r & 3) + 8 * (r >> 2) + 4 * (l >> 5);
                int node = min(n0 + row, NN - 1);
                acc[mf][nf][r] += bb + h[(size_t)node * HID + col];
            }
    }
    // per-row stats: lane partial (2 cols) -> 32-lane shuffle -> LDS cross-wave
    #pragma unroll
    for (int mf = 0; mf < 2; ++mf)
        #pragma unroll
        for (int r = 0; r < 16; ++r) {
            float v1 = acc[mf][0][r] + acc[mf][1][r];
            float v2 = acc[mf][0][r]*acc[mf][0][r] + acc[mf][1][r]*acc[mf][1][r];
            #pragma unroll
            for (int off = 16; off >= 1; off >>= 1) {
                v1 += __shfl_xor(v1, off, 64);
                v2 += __shfl_xor(v2, off, 64);
            }
            if ((l & 31) == 0) {
                int row = mh * 64 + mf * 32 + (r & 3) + 8 * (r >> 2) + 4 * (l >> 5);
                red1[ns][row] = v1; red2[ns][row] = v2;
            }
        }
    __syncthreads();
    if (tid < 128) {
        float s1 = red1[0][tid] + red1[1][tid] + red1[2][tid] + red1[3][tid];
        float s2 = red2[0][tid] + red2[1][tid] + red2[2][tid] + red2[3][tid];
        float mu = s1 * (1.0f / 256.0f);
        float var = s2 * (1.0f / 256.0f) - mu * mu;
        muS[tid] = mu;
        rsS[tid] = rsqrtf(var + 1e-5f);
    }
    __syncthreads();
    #pragma unroll
    for (int nf = 0; nf < 2; ++nf) {
        int col = ns * 64 + nf * 32 + (l & 31);
        float g = lng[col], bt = lnb[col];
        #pragma unroll
        for (int mf = 0; mf < 2; ++mf)
            #pragma unroll
            for (int r = 0; r < 16; ++r) {
                int row = mh * 64 + mf * 32 + (r & 3) + 8 * (r >> 2) + 4 * (l >> 5);
                int node = n0 + row;
                if (node < NN) {
                    float y;
                    if (ntype[node] == 1)
                        y = (acc[mf][nf][r] - muS[row]) * rsS[row] * g + bt;
                    else
                        y = h[(size_t)node * HID + col];
                    out[(size_t)node * HID + col] = y;
                }
            }
    }
}

// ===========================================================================
// fp32 fallback path (proven correct in round 1) — used if ws_size too small
// ===========================================================================
#define SWZ(k, e) ((e) ^ ((((k) >> 2) & 7) << 2))

__global__ __launch_bounds__(256) void edge_fp32(
    const float* __restrict__ h, const float* __restrict__ pos,
    const int* __restrict__ ei, const int* __restrict__ etype,
    const float* __restrict__ emb,
    const float* __restrict__ W1, const float* __restrict__ b1,
    const float* __restrict__ W2, const float* __restrict__ b2,
    float* __restrict__ seg, float* __restrict__ cnt)
{
    __shared__ float A1T[16][32];
    __shared__ float Bt[16][256];
    __shared__ float A2T[256][32];
    __shared__ float distS[32];
    __shared__ int   srcS[32], dstS[32], etS[32];
    const int tid = threadIdx.x;
    const int e0  = blockIdx.x * 32;
    if (tid < 32) {
        const int e = e0 + tid;
        const int s = ei[e];
        const int d = ei[EE + e];
        srcS[tid] = s; dstS[tid] = d; etS[tid] = etype[e];
        const float dx = pos[3*s+0] - pos[3*d+0];
        const float dy = pos[3*s+1] - pos[3*d+1];
        const float dz = pos[3*s+2] - pos[3*d+2];
        distS[tid] = sqrtf(dx*dx + dy*dy + dz*dz);
        atomicAdd(&cnt[d], 1.0f);
    }
    __syncthreads();
    const int c0 = (tid & 63) * 4;
    const int r0 = (tid >> 6) * 8;
    float acc[8][4];
    #pragma unroll
    for (int i = 0; i < 8; ++i)
        #pragma unroll
        for (int j = 0; j < 4; ++j) acc[i][j] = 0.0f;
    const float step  = 6.0f / 31.0f;
    for (int k0 = 0; k0 < 800; k0 += 16) {
        if (tid < 128) {
            const int e = tid >> 2;
            const int q = (tid & 3) * 4;
            const int k = k0 + q;
            float4 v;
            if (k < 256)       v = *(const float4*)&h[(size_t)srcS[e]*HID + k];
            else if (k < 512)  v = *(const float4*)&h[(size_t)dstS[e]*HID + (k - 256)];
            else if (k < 768)  v = *(const float4*)&emb[(size_t)etS[e]*HID + (k - 512)];
            else {
                const float de = distS[e];
                const float t0 = de - step*(float)(k-768);
                const float t1 = de - step*(float)(k-767);
                const float t2 = de - step*(float)(k-766);
                const float t3 = de - step*(float)(k-765);
                v = make_float4(__expf(-GAMMA_C*t0*t0), __expf(-GAMMA_C*t1*t1),
                                __expf(-GAMMA_C*t2*t2), __expf(-GAMMA_C*t3*t3));
            }
            A1T[q+0][e] = v.x; A1T[q+1][e] = v.y;
            A1T[q+2][e] = v.z; A1T[q+3][e] = v.w;
        }
        #pragma unroll
        for (int p = 0; p < 4; ++p) {
            const int idx = p*256 + tid;
            const int k   = idx >> 6;
            const int n   = (idx & 63) * 4;
            *(float4*)&Bt[k][n] = *(const float4*)&W1[(size_t)(k0+k)*HID + n];
        }
        __syncthreads();
        #pragma unroll
        for (int kk = 0; kk < 16; ++kk) {
            const float4 b  = *(const float4*)&Bt[kk][c0];
            const float4 a0 = *(const float4*)&A1T[kk][r0];
            const float4 a1 = *(const float4*)&A1T[kk][r0+4];
            const float a[8] = {a0.x,a0.y,a0.z,a0.w,a1.x,a1.y,a1.z,a1.w};
            #pragma unroll
            for (int i = 0; i < 8; ++i) {
                acc[i][0] = fmaf(a[i], b.x, acc[i][0]);
                acc[i][1] = fmaf(a[i], b.y, acc[i][1]);
                acc[i][2] = fmaf(a[i], b.z, acc[i][2]);
                acc[i][3] = fmaf(a[i], b.w, acc[i][3]);
            }
        }
        __syncthreads();
    }
    {
        const float4 b1v = *(const float4*)&b1[c0];
        const float bb[4] = {b1v.x, b1v.y, b1v.z, b1v.w};
        #pragma unroll
        for (int j = 0; j < 4; ++j) {
            const int k = c0 + j;
            #pragma unroll
            for (int i = 0; i < 8; ++i) {
                const float x = acc[i][j] + bb[j];
                A2T[k][SWZ(k, r0+i)] = silu_f(x);
                acc[i][j] = 0.0f;
            }
        }
    }
    __syncthreads();
    for (int k0 = 0; k0 < HID; k0 += 16) {
        #pragma unroll
        for (int p = 0; p < 4; ++p) {
            const int idx = p*256 + tid;
            const int k   = idx >> 6;
            const int n   = (idx & 63) * 4;
            *(float4*)&Bt[k][n] = *(const float4*)&W2[(size_t)(k0+k)*HID + n];
        }
        __syncthreads();
        #pragma unroll
        for (int kk = 0; kk < 16; ++kk) {
            const int K = k0 + kk;
            const float4 b  = *(const float4*)&Bt[kk][c0];
            const float4 a0 = *(const float4*)&A2T[K][SWZ(K, r0)];
            const float4 a1 = *(const float4*)&A2T[K][SWZ(K, r0+4)];
            const float a[8] = {a0.x,a0.y,a0.z,a0.w,a1.x,a1.y,a1.z,a1.w};
            #pragma unroll
            for (int i = 0; i < 8; ++i) {
                acc[i][0] = fmaf(a[i], b.x, acc[i][0]);
                acc[i][1] = fmaf(a[i], b.y, acc[i][1]);
                acc[i][2] = fmaf(a[i], b.z, acc[i][2]);
                acc[i][3] = fmaf(a[i], b.w, acc[i][3]);
            }
        }
        __syncthreads();
    }
    {
        const float4 b2v = *(const float4*)&b2[c0];
        const float bb[4] = {b2v.x, b2v.y, b2v.z, b2v.w};
        #pragma unroll
        for (int i = 0; i < 8; ++i) {
            const int d = dstS[r0 + i];
            float* outp = &seg[(size_t)d*HID + c0];
            #pragma unroll
            for (int j = 0; j < 4; ++j) {
                const float x = acc[i][j] + bb[j];
                atomicAdd(&outp[j], silu_f(x));
            }
        }
    }
}

__global__ __launch_bounds__(256) void node_fp32(
    const float* __restrict__ h, const float* __restrict__ seg,
    const float* __restrict__ cnt, const int* __restrict__ ntype,
    const float* __restrict__ W1, const float* __restrict__ b1,
    const float* __restrict__ W2, const float* __restrict__ b2,
    const float* __restrict__ lng, const float* __restrict__ lnb,
    float* __restrict__ out)
{
    __shared__ float A1T[16][32];
    __shared__ float Bt[16][256];
    __shared__ float A2T[256][32];
    __shared__ float invS[32];
    const int tid = threadIdx.x;
    const int n0  = blockIdx.x * 32;
    if (tid < 32) invS[tid] = 1.0f / fmaxf(cnt[n0 + tid], 1.0f);
    __syncthreads();
    const int c0 = (tid & 63) * 4;
    const int r0 = (tid >> 6) * 8;
    float acc[8][4];
    #pragma unroll
    for (int i = 0; i < 8; ++i)
        #pragma unroll
        for (int j = 0; j < 4; ++j) acc[i][j] = 0.0f;
    for (int k0 = 0; k0 < 512; k0 += 16) {
        if (tid < 128) {
            const int e = tid >> 2;
            const int q = (tid & 3) * 4;
            const int k = k0 + q;
            float4 v;
            if (k < 256) v = *(const float4*)&h[(size_t)(n0+e)*HID + k];
            else {
                v = *(const float4*)&seg[(size_t)(n0+e)*HID + (k - 256)];
                const float ic = invS[e];
                v.x *= ic; v.y *= ic; v.z *= ic; v.w *= ic;
            }
            A1T[q+0][e] = v.x; A1T[q+1][e] = v.y;
            A1T[q+2][e] = v.z; A1T[q+3][e] = v.w;
        }
        #pragma unroll
        for (int p = 0; p < 4; ++p) {
            const int idx = p*256 + tid;
            const int k   = idx >> 6;
            const int n   = (idx & 63) * 4;
            *(float4*)&Bt[k][n] = *(const float4*)&W1[(size_t)(k0+k)*HID + n];
        }
        __syncthreads();
        #pragma unroll
        for (int kk = 0; kk < 16; ++kk) {
            const float4 b  = *(const float4*)&Bt[kk][c0];
            const float4 a0 = *(const float4*)&A1T[kk][r0];
            const float4 a1 = *(const float4*)&A1T[kk][r0+4];
            const float a[8] = {a0.x,a0.y,a0.z,a0.w,a1.x,a1.y,a1.z,a1.w};
            #pragma unroll
            for (int i = 0; i < 8; ++i) {
                acc[i][0] = fmaf(a[i], b.x, acc[i][0]);
                acc[i][1] = fmaf(a[i], b.y, acc[i][1]);
                acc[i][2] = fmaf(a[i], b.z, acc[i][2]);
                acc[i][3] = fmaf(a[i], b.w, acc[i][3]);
            }
        }
        __syncthreads();
    }
    {
        const float4 b1v = *(const float4*)&b1[c0];
        const float bb[4] = {b1v.x, b1v.y, b1v.z, b1v.w};
        #pragma unroll
        for (int j = 0; j < 4; ++j) {
            const int k = c0 + j;
            #pragma unroll
            for (int i = 0; i < 8; ++i) {
                const float x = acc[i][j] + bb[j];
                A2T[k][SWZ(k, r0+i)] = silu_f(x);
                acc[i][j] = 0.0f;
            }
        }
    }
    __syncthreads();
    for (int k0 = 0; k0 < HID; k0 += 16) {
        #pragma unroll
        for (int p = 0; p < 4; ++p) {
            const int idx = p*256 + tid;
            const int k   = idx >> 6;
            const int n   = (idx & 63) * 4;
            *(float4*)&Bt[k][n] = *(const float4*)&W2[(size_t)(k0+k)*HID + n];
        }
        __syncthreads();
        #pragma unroll
        for (int kk = 0; kk < 16; ++kk) {
            const int K = k0 + kk;
            const float4 b  = *(const float4*)&Bt[kk][c0];
            const float4 a0 = *(const float4*)&A2T[K][SWZ(K, r0)];
            const float4 a1 = *(const float4*)&A2T[K][SWZ(K, r0+4)];
            const float a[8] = {a0.x,a0.y,a0.z,a0.w,a1.x,a1.y,a1.z,a1.w};
            #pragma unroll
            for (int i = 0; i < 8; ++i) {
                acc[i][0] = fmaf(a[i], b.x, acc[i][0]);
                acc[i][1] = fmaf(a[i], b.y, acc[i][1]);
                acc[i][2] = fmaf(a[i], b.z, acc[i][2]);
                acc[i][3] = fmaf(a[i], b.w, acc[i][3]);
            }
        }
        __syncthreads();
    }
    {
        const float4 b2v = *(const float4*)&b2[c0];
        const float bb[4] = {b2v.x, b2v.y, b2v.z, b2v.w};
        float4 hv[8];
        #pragma unroll
        for (int i = 0; i < 8; ++i) {
            hv[i] = *(const float4*)&h[(size_t)(n0+r0+i)*HID + c0];
            acc[i][0] = hv[i].x + acc[i][0] + bb[0];
            acc[i][1] = hv[i].y + acc[i][1] + bb[1];
            acc[i][2] = hv[i].z + acc[i][2] + bb[2];
            acc[i][3] = hv[i].w + acc[i][3] + bb[3];
        }
        float s1[8], s2[8];
        #pragma unroll
        for (int i = 0; i < 8; ++i) {
            s1[i] = acc[i][0] + acc[i][1] + acc[i][2] + acc[i][3];
            s2[i] = acc[i][0]*acc[i][0] + acc[i][1]*acc[i][1]
                  + acc[i][2]*acc[i][2] + acc[i][3]*acc[i][3];
        }
        #pragma unroll
        for (int off = 32; off >= 1; off >>= 1) {
            #pragma unroll
            for (int i = 0; i < 8; ++i) {
                s1[i] += __shfl_xor(s1[i], off, 64);
                s2[i] += __shfl_xor(s2[i], off, 64);
            }
        }
        const float4 gv = *(const float4*)&lng[c0];
        const float4 bv = *(const float4*)&lnb[c0];
        const float g[4] = {gv.x, gv.y, gv.z, gv.w};
        const float bb2[4] = {bv.x, bv.y, bv.z, bv.w};
        #pragma unroll
        for (int i = 0; i < 8; ++i) {
            const int n = n0 + r0 + i;
            const bool lig = (ntype[n] == 1);
            float4 y;
            if (lig) {
                const float mu  = s1[i] * (1.0f/256.0f);
                const float var = s2[i] * (1.0f/256.0f) - mu*mu;
                const float rs  = rsqrtf(var + 1e-5f);
                y.x = (acc[i][0] - mu) * rs * g[0] + bb2[0];
                y.y = (acc[i][1] - mu) * rs * g[1] + bb2[1];
                y.z = (acc[i][2] - mu) * rs * g[2] + bb2[2];
                y.w = (acc[i][3] - mu) * rs * g[3] + bb2[3];
            } else {
                y = hv[i];
            }
            *(float4*)&out[(size_t)n*HID + c0] = y;
        }
    }
}

// ===========================================================================
extern "C" void kernel_launch(void* const* d_in, const int* in_sizes, int n_in,
                              void* d_out, int out_size, void* d_ws, size_t ws_size,
                              hipStream_t stream) {
    (void)in_sizes; (void)n_in; (void)out_size;
    const float* h    = (const float*)d_in[0];
    const float* pos  = (const float*)d_in[1];
    const int*   ei   = (const int*)  d_in[2];
    const int*   et   = (const int*)  d_in[3];
    const int*   nt   = (const int*)  d_in[4];
    const float* emb  = (const float*)d_in[5];
    const float* W1m  = (const float*)d_in[6];
    const float* b1m  = (const float*)d_in[7];
    const float* W2m  = (const float*)d_in[8];
    const float* b2m  = (const float*)d_in[9];
    const float* W1u  = (const float*)d_in[10];
    const float* b1u  = (const float*)d_in[11];
    const float* W2u  = (const float*)d_in[12];
    const float* b2u  = (const float*)d_in[13];
    const float* lng  = (const float*)d_in[14];
    const float* lnb  = (const float*)d_in[15];
    float* out = (float*)d_out;

    // workspace layout (512B-aligned segments)
    size_t o = 0;
    auto al = [&](size_t b) { size_t r = o; o = (o + b + 511) & ~(size_t)511; return r; };
    const size_t o_seg  = al((size_t)NN * HID * 4);
    const size_t o_cnt  = al((size_t)NN * 4);
    const size_t o_zend = o;                       // memset range [0, o_zend)
    const size_t o_hpl  = al((size_t)2 * NN * HID * 2);
    const size_t o_emb  = al((size_t)2 * 2 * HID * 2);
    const size_t o_w1t  = al((size_t)2 * 256 * 800 * 2);
    const size_t o_w2t  = al((size_t)2 * 256 * 256 * 2);
    const size_t o_w1ut = al((size_t)2 * 256 * 512 * 2);
    const size_t o_w2ut = al((size_t)2 * 256 * 256 * 2);
    const size_t o_mipl = al((size_t)2 * NN * HID * 2);
    const size_t o_upl  = al((size_t)NN * HID * 2);
    const size_t o_mhi  = al((size_t)EE * HID * 2);
    const size_t need = o;

    char* ws = (char*)d_ws;
    float* seg = (float*)(ws + o_seg);
    float* cnt = (float*)(ws + o_cnt);

    if (ws_size >= need) {
        short* hpl   = (short*)(ws + o_hpl);
        short* embpl = (short*)(ws + o_emb);
        short* w1t   = (short*)(ws + o_w1t);
        short* w2t   = (short*)(ws + o_w2t);
        short* w1ut  = (short*)(ws + o_w1ut);
        short* w2ut  = (short*)(ws + o_w2ut);
        short* mipl  = (short*)(ws + o_mipl);
        short* upl   = (short*)(ws + o_upl);
        short* mhi   = (short*)(ws + o_mhi);

        hipMemsetAsync(d_ws, 0, o_zend, stream);
        prep_all<<<PREP_TOTAL / 256, 256, 0, stream>>>(
            h, emb, W1m, W2m, W1u, W2u, hpl, embpl, w1t, w2t, w1ut, w2ut);
        edge_mlp1<<<dim3(EE / 128, 2), 512, 0, stream>>>(
            hpl, embpl, w1t, b1m, pos, ei, et, mhi, cnt);
        edge_mlp2<<<dim3(EE / 128, 2), 512, 0, stream>>>(mhi, w2t, b2m, ei, seg);
        mi_prep<<<(NN * HID) / 256, 256, 0, stream>>>(seg, cnt, mipl);
        const int nb = (NN + 127) / 128;
        node_mlp1<<<nb, 512, 0, stream>>>(hpl, mipl, w1ut, b1u, upl);
        node_mlp2<<<nb, 512, 0, stream>>>(upl, w2ut, b2u, h, nt, lng, lnb, out);
    } else {
        // fp32 fallback (round-1 kernels)
        hipMemsetAsync(d_ws, 0, ((size_t)NN * HID + NN) * sizeof(float), stream);
        float* seg0 = (float*)d_ws;
        float* cnt0 = seg0 + (size_t)NN * HID;
        edge_fp32<<<EE / 32, 256, 0, stream>>>(h, pos, ei, et, emb,
                                               W1m, b1m, W2m, b2m, seg0, cnt0);
        node_fp32<<<NN / 32, 256, 0, stream>>>(h, seg0, cnt0, nt,
                                               W1u, b1u, W2u, b2u, lng, lnb, out);
    }
}

// Round 5
// 872.406 us; speedup vs baseline: 3.4340x; 1.0727x over previous
//
#include <hip/hip_runtime.h>
#include <hip/hip_fp16.h>
#include <math.h>

#define NN   20000
#define EE   320000
#define HID  256
#define K1P  544      // folded K: 512 (h src/dst) + 32 (RBF); emb folded into T
#define GAMMA_C ((31.0f/6.0f)*(31.0f/6.0f))   // 1/step^2, step = 6/31

typedef __attribute__((ext_vector_type(8)))  short    short8;   // 8 bf16 bits
typedef __attribute__((ext_vector_type(8)))  _Float16 half8;    // 8 fp16
typedef __attribute__((ext_vector_type(16))) float    f32x16;

__device__ __forceinline__ float silu_f(float x) {
    return x / (1.0f + __expf(-x));
}

// fp32 -> bf16 RNE bits
__device__ __forceinline__ short bf_hi(float x) {
    unsigned u = __float_as_uint(x);
    return (short)((u + 0x7fffu + ((u >> 16) & 1u)) >> 16);
}
__device__ __forceinline__ float bf_tof(short b) {
    return __uint_as_float(((unsigned)(unsigned short)b) << 16);
}
__device__ __forceinline__ void cvt_bf16_pair(float x, short* hi, short* lo) {
    short h = bf_hi(x);
    *hi = h;
    *lo = bf_hi(x - bf_tof(h));
}
__device__ __forceinline__ void cvt_f16_pair(float x, short* hi, short* lo) {
    __half h = __float2half_rn(x);
    *hi = (short)__half_as_ushort(h);
    *lo = (short)__half_as_ushort(__float2half_rn(x - __half2float(h)));
}
__device__ __forceinline__ short f16_bits(float x) {
    return (short)__half_as_ushort(__float2half_rn(x));
}

// async global->LDS, 16B per lane; LDS dest = uniform base + lane*16
typedef __attribute__((address_space(1))) const void GV;
typedef __attribute__((address_space(3))) void LV;
__device__ __forceinline__ void gll16(const void* g, void* l) {
    __builtin_amdgcn_global_load_lds((GV*)g, (LV*)l, 16, 0, 0);
}

// 128B rows = 8 slots of 16B; physical slot = sg ^ (row&7) (involution on
// both stage-source and read side — rule #21).
__device__ __forceinline__ short8 ldsfrag(const short* t, int row, int sg) {
    int s = sg ^ (row & 7);
    return *(const short8*)&t[row * 64 + s * 8];
}
// 64B rows = 4 slots of 16B; slot = sg ^ (row&3)
__device__ __forceinline__ half8 ldsfragh32(const short* t, int row, int sg) {
    int s = sg ^ (row & 3);
    return *(const half8*)&t[row * 32 + s * 8];
}
__device__ __forceinline__ half8 ldsfragh(const short* t, int row, int sg) {
    int s = sg ^ (row & 7);
    return *(const half8*)&t[row * 64 + s * 8];
}

// ---------------------------------------------------------------------------
// prep: fp32 -> split planes.  bf16 pairs: h, emb, W1m^T(folded), W1u^T.
//       f16 pairs: W2m^T, W2u^T.
// w1t layout: [256 cols][544 k'] where k'<512 -> orig k (src/dst halves),
//             k'>=512 -> orig k+256 (RBF rows 768..799). emb rows folded out.
// ---------------------------------------------------------------------------
#define S0 (NN*HID)     // h        5,120,000
#define S1 (2*HID)      // emb      512
#define S2 (256*544)    // W1t      139,264
#define S3 (256*256)    // W2t      65,536
#define S4 (256*512)    // W1ut     131,072
#define S5 (256*256)    // W2ut     65,536
#define PREP_TOTAL (S0+S1+S2+S3+S4+S5)   // 5,521,920 = 21570*256

__global__ __launch_bounds__(256) void prep_all(
    const float* __restrict__ h, const float* __restrict__ emb,
    const float* __restrict__ W1m, const float* __restrict__ W2m,
    const float* __restrict__ W1u, const float* __restrict__ W2u,
    short* __restrict__ hpl, short* __restrict__ embpl,
    short* __restrict__ w1t, short* __restrict__ w2t,
    short* __restrict__ w1ut, short* __restrict__ w2ut)
{
    int i = blockIdx.x * 256 + threadIdx.x;
    float x; short *hi, *lo; int o; int f16 = 0;
    if (i < S0)              { x = h[i];   hi = hpl;   lo = hpl + S0;   o = i; }
    else if ((i -= S0) < S1) { x = emb[i]; hi = embpl; lo = embpl + S1; o = i; }
    else if ((i -= S1) < S2) { int n = i / 544, k = i - n * 544;
                               int ok = (k < 512) ? k : (k + 256);
                               x = W1m[ok * 256 + n]; hi = w1t; lo = w1t + S2; o = i; }
    else if ((i -= S2) < S3) { int n = i >> 8, k = i & 255;
                               x = W2m[k * 256 + n]; hi = w2t; lo = w2t + S3; o = i; f16 = 1; }
    else if ((i -= S3) < S4) { int n = i >> 9, k = i & 511;
                               x = W1u[k * 256 + n]; hi = w1ut; lo = w1ut + S4; o = i; }
    else if ((i -= S4) < S5) { int n = i >> 8, k = i & 255;
                               x = W2u[k * 256 + n]; hi = w2ut; lo = w2ut + S5; o = i; f16 = 1; }
    else return;
    short hb, lb;
    if (f16) cvt_f16_pair(x, &hb, &lb); else cvt_bf16_pair(x, &hb, &lb);
    hi[o] = hb; lo[o] = lb;
}

// ---------------------------------------------------------------------------
// tprep: T[e][n] = b1m[n] + sum_k emb[e][k] * W1m[512+k][n]   (exact fp32)
// ---------------------------------------------------------------------------
__global__ __launch_bounds__(512) void tprep(
    const float* __restrict__ W1m, const float* __restrict__ b1,
    const float* __restrict__ emb, float* __restrict__ T)
{
    int tid = threadIdx.x;
    int e = tid >> 8, n = tid & 255;
    float s = b1[n];
    for (int k = 0; k < 256; ++k)
        s += emb[e * 256 + k] * W1m[(512 + k) * 256 + n];
    T[e * 256 + n] = s;
}

// ---------------------------------------------------------------------------
// edge_mlp1 v3: m = silu(hs@W1a + hd@W1b + radial@W1c + T[et]) -> fp16 plane.
// Block = 256 edges x 256 cols, 512 thr, 8 waves (2 mh x 4 ns),
// wave tile 128x64 -> acc[4][2] (128 AGPR). 1 block/CU (132 KB LDS).
// 24 ds_read_b128 per 48 MFMA per chunk -> MFMA-bound on the LDS unit.
// K=544 in 17 chunks of 32 (chunk 16 = RBF via ds_write).
// 2-deep dbuf + COUNTED vmcnt (T4): wait vmcnt(8) for the older stage only;
// raw s_barrier (no drain); loads for chunk c+1 stay in flight across it.
// ---------------------------------------------------------------------------
__global__ __launch_bounds__(512, 2) void edge_mlp1(
    const short* __restrict__ hpl, const short* __restrict__ w1t,
    const float* __restrict__ Ttab, const float* __restrict__ pos,
    const int* __restrict__ ei, const int* __restrict__ etype,
    short* __restrict__ mhi, float* __restrict__ cnt)
{
    __shared__ __align__(16) short At[2][256 * 64];   // 2 x 32 KB
    __shared__ __align__(16) short Bt[2][256 * 64];   // 2 x 32 KB
    __shared__ int srcS[256], dstS[256], etS[256];
    __shared__ float distS[256];

    const int tid = threadIdx.x, l = tid & 63, w = tid >> 6;
    const int e0 = blockIdx.x * 256;
    const int mh = w >> 2, ns = w & 3;

    if (tid < 256) {
        int s = ei[e0 + tid], d = ei[EE + e0 + tid];
        srcS[tid] = s; dstS[tid] = d; etS[tid] = etype[e0 + tid];
        float dx = pos[3*s]   - pos[3*d];
        float dy = pos[3*s+1] - pos[3*d+1];
        float dz = pos[3*s+2] - pos[3*d+2];
        distS[tid] = sqrtf(dx*dx + dy*dy + dz*dz);
        atomicAdd(&cnt[d], 1.0f);
    }
    __syncthreads();

    // per-thread staging constants (32-bit element offsets; base ptr stays SGPR)
    unsigned offS[4], offD[4], offB[4];
    #pragma unroll
    for (int jj = 0; jj < 4; ++jj) {
        int j = w * 4 + jj;
        int row = j * 8 + (l >> 3), s = l & 7;
        int sg = s ^ (row & 7);
        int hl = sg >> 2, q = sg & 3;
        offS[jj] = (unsigned)hl * (NN*HID) + (unsigned)srcS[row] * HID + q*8;
        offD[jj] = (unsigned)hl * (NN*HID) + (unsigned)dstS[row] * HID + q*8;
        offB[jj] = (unsigned)hl * (256*544) + (unsigned)row * 544 + q*8;
    }

    auto stage = [&](int buf, int c) {
        if (c < 16) {
            #pragma unroll
            for (int jj = 0; jj < 4; ++jj) {
                const short* gp = (c < 8) ? (hpl + offS[jj] + c*32)
                                          : (hpl + offD[jj] + (c-8)*32);
                gll16(gp, &At[buf][(w*4 + jj) * 512]);
            }
        } else {
            // RBF chunk (k' 512..543): compute + swizzled ds_write
            #pragma unroll
            for (int jj = 0; jj < 4; ++jj) {
                int it = tid * 4 + jj;
                int row = it >> 3, s = it & 7;
                int sg = s ^ (row & 7);
                int hl = sg >> 2, q = sg & 3;
                float d = distS[row];
                short8 v;
                #pragma unroll
                for (int k8 = 0; k8 < 8; ++k8) {
                    float cen = (float)(q * 8 + k8) * (6.0f / 31.0f);
                    float t = d - cen;
                    float f = __expf(-GAMMA_C * t * t);
                    short hb = bf_hi(f);
                    v[k8] = hl ? bf_hi(f - bf_tof(hb)) : hb;
                }
                *(short8*)&At[buf][row * 64 + s * 8] = v;
            }
            // drain own ds_writes; barriers before compute(16) order cross-wave
            asm volatile("s_waitcnt lgkmcnt(0)" ::: "memory");
        }
        #pragma unroll
        for (int jj = 0; jj < 4; ++jj)
            gll16(w1t + offB[jj] + c*32, &Bt[buf][(w*4 + jj) * 512]);
    };

    f32x16 acc[4][2];
    #pragma unroll
    for (int a = 0; a < 4; ++a)
        #pragma unroll
        for (int b = 0; b < 2; ++b)
            #pragma unroll
            for (int q = 0; q < 16; ++q) acc[a][b][q] = 0.0f;

    // prologue: 2 stages in flight (8 loads each)
    stage(0, 0);
    stage(1, 1);

    for (int c = 0; c <= 16; ++c) {
        // wait for stage(c) only; stage(c+1) stays in flight across the barrier
        if (c <= 14)      asm volatile("s_waitcnt vmcnt(8)" ::: "memory");
        else if (c == 15) asm volatile("s_waitcnt vmcnt(4)" ::: "memory");
        else              asm volatile("s_waitcnt vmcnt(0)" ::: "memory");
        __builtin_amdgcn_s_barrier();
        __builtin_amdgcn_sched_barrier(0);

        const int buf = c & 1;
        #pragma unroll
        for (int t2 = 0; t2 < 2; ++t2) {
            short8 bF[2][2];
            #pragma unroll
            for (int nf = 0; nf < 2; ++nf)
                #pragma unroll
                for (int hl = 0; hl < 2; ++hl)
                    bF[nf][hl] = ldsfrag(&Bt[buf][0], ns*64 + nf*32 + (l & 31),
                                         hl*4 + t2*2 + (l >> 5));
            #pragma unroll
            for (int mf = 0; mf < 4; ++mf) {
                int arow = mh*128 + mf*32 + (l & 31);
                short8 aF0 = ldsfrag(&At[buf][0], arow, 0*4 + t2*2 + (l >> 5));
                short8 aF1 = ldsfrag(&At[buf][0], arow, 1*4 + t2*2 + (l >> 5));
                #pragma unroll
                for (int nf = 0; nf < 2; ++nf) {
                    acc[mf][nf] = __builtin_amdgcn_mfma_f32_32x32x16_bf16(aF0, bF[nf][0], acc[mf][nf], 0, 0, 0);
                    acc[mf][nf] = __builtin_amdgcn_mfma_f32_32x32x16_bf16(aF0, bF[nf][1], acc[mf][nf], 0, 0, 0);
                    acc[mf][nf] = __builtin_amdgcn_mfma_f32_32x32x16_bf16(aF1, bF[nf][0], acc[mf][nf], 0, 0, 0);
                }
            }
        }

        __builtin_amdgcn_sched_barrier(0);
        __builtin_amdgcn_s_barrier();          // all waves done reading buf
        if (c + 2 <= 16) stage(buf, c + 2);    // overwrite the freed buffer
    }

    // epilogue: + T[et][col], silu -> fp16 m plane
    #pragma unroll
    for (int nf = 0; nf < 2; ++nf) {
        int col = ns*64 + nf*32 + (l & 31);
        #pragma unroll
        for (int mf = 0; mf < 4; ++mf)
            #pragma unroll
            for (int r = 0; r < 16; ++r) {
                int row = mh*128 + mf*32 + (r & 3) + 8*(r >> 2) + 4*(l >> 5);
                float tv = Ttab[etS[row] * 256 + col];
                float v = silu_f(acc[mf][nf][r] + tv);
                mhi[(size_t)(e0 + row) * HID + col] = f16_bits(v);
            }
    }
}

// ---------------------------------------------------------------------------
// edge_mlp2: m_ij = silu(m @ W2m + b2m); atomicAdd into seg[dst].
// (round-4 passing version, unchanged)
// ---------------------------------------------------------------------------
__global__ __launch_bounds__(512, 4) void edge_mlp2(
    const short* __restrict__ mhi, const short* __restrict__ w2t,
    const float* __restrict__ b2, const int* __restrict__ ei,
    float* __restrict__ seg)
{
    __shared__ __align__(16) short Ah[2][128 * 32];   // 2 x 8 KB
    __shared__ __align__(16) short Bh[2][128 * 32];
    __shared__ __align__(16) short Bl[2][128 * 32];
    __shared__ int dstS[128];
    const int tid = threadIdx.x, l = tid & 63, w = tid >> 6;
    const int e0 = blockIdx.x * 128;
    const int cb = blockIdx.y;
    const int mh = w >> 2, ns = w & 3;
    if (tid < 128) dstS[tid] = ei[EE + e0 + tid];
    __syncthreads();

    auto stageA = [&](int buf, int c) {
        int row = w * 16 + (l >> 2), s = l & 3;
        int sg = s ^ (row & 3);
        gll16(mhi + (size_t)(e0 + row) * HID + c * 32 + sg * 8, &Ah[buf][w * 512]);
    };
    auto stageB = [&](int buf, int c) {
        #pragma unroll
        for (int jj = 0; jj < 2; ++jj) {
            int j = w * 2 + jj;
            int hf = j >> 3, jn = j & 7;
            int n = jn * 16 + (l >> 2), s = l & 3;
            int sg = s ^ (n & 3);
            const short* gp = w2t + (size_t)hf * (256*256)
                            + (size_t)(cb*128 + n) * HID + c * 32 + sg * 8;
            gll16(gp, hf ? &Bl[buf][jn * 512] : &Bh[buf][jn * 512]);
        }
    };

    f32x16 acc[2];
    #pragma unroll
    for (int a = 0; a < 2; ++a)
        #pragma unroll
        for (int q = 0; q < 16; ++q) acc[a][q] = 0.0f;

    stageA(0, 0); stageB(0, 0);
    __syncthreads();

    int cur = 0;
    for (int c = 0; c < 8; ++c) {
        if (c < 7) { stageA(cur ^ 1, c + 1); stageB(cur ^ 1, c + 1); }
        #pragma unroll
        for (int t2 = 0; t2 < 2; ++t2) {
            int sg = t2 * 2 + (l >> 5);
            half8 aF[2], bH, bL;
            #pragma unroll
            for (int mf = 0; mf < 2; ++mf)
                aF[mf] = ldsfragh32(&Ah[cur][0], mh * 64 + mf * 32 + (l & 31), sg);
            {
                int n = ns * 32 + (l & 31);
                bH = ldsfragh32(&Bh[cur][0], n, sg);
                bL = ldsfragh32(&Bl[cur][0], n, sg);
            }
            #pragma unroll
            for (int mf = 0; mf < 2; ++mf) {
                acc[mf] = __builtin_amdgcn_mfma_f32_32x32x16_f16(aF[mf], bH, acc[mf], 0, 0, 0);
                acc[mf] = __builtin_amdgcn_mfma_f32_32x32x16_f16(aF[mf], bL, acc[mf], 0, 0, 0);
            }
        }
        __syncthreads();
        cur ^= 1;
    }

    {
        int col = cb * 128 + ns * 32 + (l & 31);
        float bb = b2[col];
        #pragma unroll
        for (int mf = 0; mf < 2; ++mf)
            #pragma unroll
            for (int r = 0; r < 16; ++r) {
                int row = mh * 64 + mf * 32 + (r & 3) + 8 * (r >> 2) + 4 * (l >> 5);
                float v = silu_f(acc[mf][r] + bb);
                atomicAdd(&seg[(size_t)dstS[row] * HID + col], v);
            }
    }
}

// ---------------------------------------------------------------------------
// mi_prep: m_i = seg / max(cnt,1) -> bf16 hi/lo planes
// ---------------------------------------------------------------------------
__global__ __launch_bounds__(256) void mi_prep(
    const float* __restrict__ seg, const float* __restrict__ cnt,
    short* __restrict__ mipl)
{
    int i = blockIdx.x * 256 + threadIdx.x;
    int row = i >> 8;
    float v = seg[i] / fmaxf(cnt[row], 1.0f);
    short hb, lb;
    cvt_bf16_pair(v, &hb, &lb);
    mipl[i] = hb;
    mipl[(size_t)NN * HID + i] = lb;
}

// ---------------------------------------------------------------------------
// node_mlp1: u = silu([h, m_i] @ W1u + b1u) -> fp16 plane. K=512, 16 chunks.
// (round-3/4 passing version, unchanged)
// ---------------------------------------------------------------------------
__global__ __launch_bounds__(512) void node_mlp1(
    const short* __restrict__ hpl, const short* __restrict__ mipl,
    const short* __restrict__ w1ut, const float* __restrict__ b1,
    short* __restrict__ u)
{
    __shared__ __align__(16) short At[128 * 64];
    __shared__ __align__(16) short Bt[256 * 64];
    const int tid = threadIdx.x, l = tid & 63, w = tid >> 6;
    const int n0 = blockIdx.x * 128;
    const int mh = w >> 2, ns = w & 3;

    f32x16 acc[2][2];
    #pragma unroll
    for (int a = 0; a < 2; ++a)
        #pragma unroll
        for (int b = 0; b < 2; ++b)
            #pragma unroll
            for (int q = 0; q < 16; ++q) acc[a][b][q] = 0.0f;

    for (int c = 0; c < 16; ++c) {
        #pragma unroll
        for (int jj = 0; jj < 2; ++jj) {
            int j = w * 2 + jj;
            int row = j * 8 + (l >> 3), s = l & 7;
            int sg = s ^ (row & 7);
            int hl = sg >> 2, q = sg & 3;
            int node = min(n0 + row, NN - 1);
            const short* gp = (c < 8)
                ? hpl  + (size_t)hl * (NN*HID) + (size_t)node * HID + c * 32 + q * 8
                : mipl + (size_t)hl * (NN*HID) + (size_t)node * HID + (c - 8) * 32 + q * 8;
            gll16(gp, &At[j * 512]);
        }
        #pragma unroll
        for (int jj = 0; jj < 4; ++jj) {
            int j = w * 4 + jj;
            int n = j * 8 + (l >> 3), s = l & 7;
            int sg = s ^ (n & 7);
            int hl = sg >> 2, q = sg & 3;
            const short* gp = w1ut + (size_t)hl * (256*512) + n * 512 + c * 32 + q * 8;
            gll16(gp, &Bt[j * 512]);
        }
        __syncthreads();
        #pragma unroll
        for (int t2 = 0; t2 < 2; ++t2) {
            short8 aF[2][2], bF[2][2];
            #pragma unroll
            for (int mf = 0; mf < 2; ++mf) {
                int row = mh * 64 + mf * 32 + (l & 31);
                #pragma unroll
                for (int hl = 0; hl < 2; ++hl)
                    aF[mf][hl] = ldsfrag(At, row, hl * 4 + t2 * 2 + (l >> 5));
            }
            #pragma unroll
            for (int nf = 0; nf < 2; ++nf) {
                int n = ns * 64 + nf * 32 + (l & 31);
                #pragma unroll
                for (int hl = 0; hl < 2; ++hl)
                    bF[nf][hl] = ldsfrag(Bt, n, hl * 4 + t2 * 2 + (l >> 5));
            }
            #pragma unroll
            for (int mf = 0; mf < 2; ++mf)
                #pragma unroll
                for (int nf = 0; nf < 2; ++nf) {
                    acc[mf][nf] = __builtin_amdgcn_mfma_f32_32x32x16_bf16(aF[mf][0], bF[nf][0], acc[mf][nf], 0, 0, 0);
                    acc[mf][nf] = __builtin_amdgcn_mfma_f32_32x32x16_bf16(aF[mf][0], bF[nf][1], acc[mf][nf], 0, 0, 0);
                    acc[mf][nf] = __builtin_amdgcn_mfma_f32_32x32x16_bf16(aF[mf][1], bF[nf][0], acc[mf][nf], 0, 0, 0);
                }
        }
        __syncthreads();
    }
    #pragma unroll
    for (int nf = 0; nf < 2; ++nf) {
        int col = ns * 64 + nf * 32 + (l & 31);
        float bb = b1[col];
        #pragma unroll
        for (int mf = 0; mf < 2; ++mf)
            #pragma unroll
            for (int r = 0; r < 16; ++r) {
                int row = mh * 64 + mf * 32 + (r & 3) + 8 * (r >> 2) + 4 * (l >> 5);
                if (n0 + row < NN) {
                    float v = silu_f(acc[mf][nf][r] + bb);
                    u[(size_t)(n0 + row) * HID + col] = f16_bits(v);
                }
            }
    }
}

// ---------------------------------------------------------------------------
// node_mlp2: upd = u @ W2u + b2u; out = lig ? LN(h+upd)*g+b : h
// (round-3/4 passing version, unchanged)
// ---------------------------------------------------------------------------
__global__ __launch_bounds__(512) void node_mlp2(
    const short* __restrict__ u, const short* __restrict__ w2ut,
    const float* __restrict__ b2, const float* __restrict__ h,
    const int* __restrict__ ntype, const float* __restrict__ lng,
    const float* __restrict__ lnb, float* __restrict__ out)
{
    __shared__ __align__(16) short Ah[128 * 64];
    __shared__ __align__(16) short Bh[256 * 64];
    __shared__ __align__(16) short Bl[256 * 64];
    __shared__ float red1[4][128], red2[4][128];
    __shared__ float muS[128], rsS[128];
    const int tid = threadIdx.x, l = tid & 63, w = tid >> 6;
    const int n0 = blockIdx.x * 128;
    const int mh = w >> 2, ns = w & 3;

    f32x16 acc[2][2];
    #pragma unroll
    for (int a = 0; a < 2; ++a)
        #pragma unroll
        for (int b = 0; b < 2; ++b)
            #pragma unroll
            for (int q = 0; q < 16; ++q) acc[a][b][q] = 0.0f;

    for (int c = 0; c < 4; ++c) {
        #pragma unroll
        for (int jj = 0; jj < 2; ++jj) {
            int j = w * 2 + jj;
            int row = j * 8 + (l >> 3), s = l & 7;
            int sg = s ^ (row & 7);
            int node = min(n0 + row, NN - 1);
            gll16(u + (size_t)node * HID + c * 64 + sg * 8, &Ah[j * 512]);
        }
        #pragma unroll
        for (int jj = 0; jj < 8; ++jj) {
            int j = w * 8 + jj;
            int hf = j >> 5;
            int n = (j & 31) * 8 + (l >> 3), s = l & 7;
            int sg = s ^ (n & 7);
            const short* gp = w2ut + (size_t)hf * (256*256) + n * HID + c * 64 + sg * 8;
            gll16(gp, hf ? &Bl[(j & 31) * 512] : &Bh[(j & 31) * 512]);
        }
        __syncthreads();
        #pragma unroll
        for (int t2 = 0; t2 < 4; ++t2) {
            int sg = t2 * 2 + (l >> 5);
            half8 aF[2], bH[2], bL[2];
            #pragma unroll
            for (int mf = 0; mf < 2; ++mf)
                aF[mf] = ldsfragh(Ah, mh * 64 + mf * 32 + (l & 31), sg);
            #pragma unroll
            for (int nf = 0; nf < 2; ++nf) {
                int n = ns * 64 + nf * 32 + (l & 31);
                bH[nf] = ldsfragh(Bh, n, sg);
                bL[nf] = ldsfragh(Bl, n, sg);
            }
            #pragma unroll
            for (int mf = 0; mf < 2; ++mf)
                #pragma unroll
                for (int nf = 0; nf < 2; ++nf) {
                    acc[mf][nf] = __builtin_amdgcn_mfma_f32_32x32x16_f16(aF[mf], bH[nf], acc[mf][nf], 0, 0, 0);
                    acc[mf][nf] = __builtin_amdgcn_mfma_f32_32x32x16_f16(aF[mf], bL[nf], acc[mf][nf], 0, 0, 0);
                }
        }
        __syncthreads();
    }

    #pragma unroll
    for (int nf = 0; nf < 2; ++nf) {
        int col = ns * 64 + nf * 32 + (l & 31);
        float bb = b2[col];
        #pragma unroll
        for (int mf = 0; mf < 2; ++mf)
            #pragma unroll
            for (int r = 0; r < 16; ++r) {
                int row = mh * 64 + mf * 32 + (r & 3) + 8 * (r >> 2) + 4 * (l >> 5);
                int node = min(n0 + row, NN - 1);
                acc[mf][nf][r] += bb + h[(size_t)node * HID + col];
            }
    }
    #pragma unroll
    for (int mf = 0; mf < 2; ++mf)
        #pragma unroll
        for (int r = 0; r < 16; ++r) {
            float v1 = acc[mf][0][r] + acc[mf][1][r];
            float v2 = acc[mf][0][r]*acc[mf][0][r] + acc[mf][1][r]*acc[mf][1][r];
            #pragma unroll
            for (int off = 16; off >= 1; off >>= 1) {
                v1 += __shfl_xor(v1, off, 64);
                v2 += __shfl_xor(v2, off, 64);
            }
            if ((l & 31) == 0) {
                int row = mh * 64 + mf * 32 + (r & 3) + 8 * (r >> 2) + 4 * (l >> 5);
                red1[ns][row] = v1; red2[ns][row] = v2;
            }
        }
    __syncthreads();
    if (tid < 128) {
        float s1 = red1[0][tid] + red1[1][tid] + red1[2][tid] + red1[3][tid];
        float s2 = red2[0][tid] + red2[1][tid] + red2[2][tid] + red2[3][tid];
        float mu = s1 * (1.0f / 256.0f);
        float var = s2 * (1.0f / 256.0f) - mu * mu;
        muS[tid] = mu;
        rsS[tid] = rsqrtf(var + 1e-5f);
    }
    __syncthreads();
    #pragma unroll
    for (int nf = 0; nf < 2; ++nf) {
        int col = ns * 64 + nf * 32 + (l & 31);
        float g = lng[col], bt = lnb[col];
        #pragma unroll
        for (int mf = 0; mf < 2; ++mf)
            #pragma unroll
            for (int r = 0; r < 16; ++r) {
                int row = mh * 64 + mf * 32 + (r & 3) + 8 * (r >> 2) + 4 * (l >> 5);
                int node = n0 + row;
                if (node < NN) {
                    float y;
                    if (ntype[node] == 1)
                        y = (acc[mf][nf][r] - muS[row]) * rsS[row] * g + bt;
                    else
                        y = h[(size_t)node * HID + col];
                    out[(size_t)node * HID + col] = y;
                }
            }
    }
}

// ===========================================================================
// fp32 fallback path (proven correct in round 1) — used if ws_size too small
// ===========================================================================
#define SWZ(k, e) ((e) ^ ((((k) >> 2) & 7) << 2))

__global__ __launch_bounds__(256) void edge_fp32(
    const float* __restrict__ h, const float* __restrict__ pos,
    const int* __restrict__ ei, const int* __restrict__ etype,
    const float* __restrict__ emb,
    const float* __restrict__ W1, const float* __restrict__ b1,
    const float* __restrict__ W2, const float* __restrict__ b2,
    float* __restrict__ seg, float* __restrict__ cnt)
{
    __shared__ float A1T[16][32];
    __shared__ float Bt[16][256];
    __shared__ float A2T[256][32];
    __shared__ float distS[32];
    __shared__ int   srcS[32], dstS[32], etS[32];
    const int tid = threadIdx.x;
    const int e0  = blockIdx.x * 32;
    if (tid < 32) {
        const int e = e0 + tid;
        const int s = ei[e];
        const int d = ei[EE + e];
        srcS[tid] = s; dstS[tid] = d; etS[tid] = etype[e];
        const float dx = pos[3*s+0] - pos[3*d+0];
        const float dy = pos[3*s+1] - pos[3*d+1];
        const float dz = pos[3*s+2] - pos[3*d+2];
        distS[tid] = sqrtf(dx*dx + dy*dy + dz*dz);
        atomicAdd(&cnt[d], 1.0f);
    }
    __syncthreads();
    const int c0 = (tid & 63) * 4;
    const int r0 = (tid >> 6) * 8;
    float acc[8][4];
    #pragma unroll
    for (int i = 0; i < 8; ++i)
        #pragma unroll
        for (int j = 0; j < 4; ++j) acc[i][j] = 0.0f;
    const float step  = 6.0f / 31.0f;
    for (int k0 = 0; k0 < 800; k0 += 16) {
        if (tid < 128) {
            const int e = tid >> 2;
            const int q = (tid & 3) * 4;
            const int k = k0 + q;
            float4 v;
            if (k < 256)       v = *(const float4*)&h[(size_t)srcS[e]*HID + k];
            else if (k < 512)  v = *(const float4*)&h[(size_t)dstS[e]*HID + (k - 256)];
            else if (k < 768)  v = *(const float4*)&emb[(size_t)etS[e]*HID + (k - 512)];
            else {
                const float de = distS[e];
                const float t0 = de - step*(float)(k-768);
                const float t1 = de - step*(float)(k-767);
                const float t2 = de - step*(float)(k-766);
                const float t3 = de - step*(float)(k-765);
                v = make_float4(__expf(-GAMMA_C*t0*t0), __expf(-GAMMA_C*t1*t1),
                                __expf(-GAMMA_C*t2*t2), __expf(-GAMMA_C*t3*t3));
            }
            A1T[q+0][e] = v.x; A1T[q+1][e] = v.y;
            A1T[q+2][e] = v.z; A1T[q+3][e] = v.w;
        }
        #pragma unroll
        for (int p = 0; p < 4; ++p) {
            const int idx = p*256 + tid;
            const int k   = idx >> 6;
            const int n   = (idx & 63) * 4;
            *(float4*)&Bt[k][n] = *(const float4*)&W1[(size_t)(k0+k)*HID + n];
        }
        __syncthreads();
        #pragma unroll
        for (int kk = 0; kk < 16; ++kk) {
            const float4 b  = *(const float4*)&Bt[kk][c0];
            const float4 a0 = *(const float4*)&A1T[kk][r0];
            const float4 a1 = *(const float4*)&A1T[kk][r0+4];
            const float a[8] = {a0.x,a0.y,a0.z,a0.w,a1.x,a1.y,a1.z,a1.w};
            #pragma unroll
            for (int i = 0; i < 8; ++i) {
                acc[i][0] = fmaf(a[i], b.x, acc[i][0]);
                acc[i][1] = fmaf(a[i], b.y, acc[i][1]);
                acc[i][2] = fmaf(a[i], b.z, acc[i][2]);
                acc[i][3] = fmaf(a[i], b.w, acc[i][3]);
            }
        }
        __syncthreads();
    }
    {
        const float4 b1v = *(const float4*)&b1[c0];
        const float bb[4] = {b1v.x, b1v.y, b1v.z, b1v.w};
        #pragma unroll
        for (int j = 0; j < 4; ++j) {
            const int k = c0 + j;
            #pragma unroll
            for (int i = 0; i < 8; ++i) {
                const float x = acc[i][j] + bb[j];
                A2T[k][SWZ(k, r0+i)] = silu_f(x);
                acc[i][j] = 0.0f;
            }
        }
    }
    __syncthreads();
    for (int k0 = 0; k0 < HID; k0 += 16) {
        #pragma unroll
        for (int p = 0; p < 4; ++p) {
            const int idx = p*256 + tid;
            const int k   = idx >> 6;
            const int n   = (idx & 63) * 4;
            *(float4*)&Bt[k][n] = *(const float4*)&W2[(size_t)(k0+k)*HID + n];
        }
        __syncthreads();
        #pragma unroll
        for (int kk = 0; kk < 16; ++kk) {
            const int K = k0 + kk;
            const float4 b  = *(const float4*)&Bt[kk][c0];
            const float4 a0 = *(const float4*)&A2T[K][SWZ(K, r0)];
            const float4 a1 = *(const float4*)&A2T[K][SWZ(K, r0+4)];
            const float a[8] = {a0.x,a0.y,a0.z,a0.w,a1.x,a1.y,a1.z,a1.w};
            #pragma unroll
            for (int i = 0; i < 8; ++i) {
                acc[i][0] = fmaf(a[i], b.x, acc[i][0]);
                acc[i][1] = fmaf(a[i], b.y, acc[i][1]);
                acc[i][2] = fmaf(a[i], b.z, acc[i][2]);
                acc[i][3] = fmaf(a[i], b.w, acc[i][3]);
            }
        }
        __syncthreads();
    }
    {
        const float4 b2v = *(const float4*)&b2[c0];
        const float bb[4] = {b2v.x, b2v.y, b2v.z, b2v.w};
        #pragma unroll
        for (int i = 0; i < 8; ++i) {
            const int d = dstS[r0 + i];
            float* outp = &seg[(size_t)d*HID + c0];
            #pragma unroll
            for (int j = 0; j < 4; ++j) {
                const float x = acc[i][j] + bb[j];
                atomicAdd(&outp[j], silu_f(x));
            }
        }
    }
}

__global__ __launch_bounds__(256) void node_fp32(
    const float* __restrict__ h, const float* __restrict__ seg,
    const float* __restrict__ cnt, const int* __restrict__ ntype,
    const float* __restrict__ W1, const float* __restrict__ b1,
    const float* __restrict__ W2, const float* __restrict__ b2,
    const float* __restrict__ lng, const float* __restrict__ lnb,
    float* __restrict__ out)
{
    __shared__ float A1T[16][32];
    __shared__ float Bt[16][256];
    __shared__ float A2T[256][32];
    __shared__ float invS[32];
    const int tid = threadIdx.x;
    const int n0  = blockIdx.x * 32;
    if (tid < 32) invS[tid] = 1.0f / fmaxf(cnt[n0 + tid], 1.0f);
    __syncthreads();
    const int c0 = (tid & 63) * 4;
    const int r0 = (tid >> 6) * 8;
    float acc[8][4];
    #pragma unroll
    for (int i = 0; i < 8; ++i)
        #pragma unroll
        for (int j = 0; j < 4; ++j) acc[i][j] = 0.0f;
    for (int k0 = 0; k0 < 512; k0 += 16) {
        if (tid < 128) {
            const int e = tid >> 2;
            const int q = (tid & 3) * 4;
            const int k = k0 + q;
            float4 v;
            if (k < 256) v = *(const float4*)&h[(size_t)(n0+e)*HID + k];
            else {
                v = *(const float4*)&seg[(size_t)(n0+e)*HID + (k - 256)];
                const float ic = invS[e];
                v.x *= ic; v.y *= ic; v.z *= ic; v.w *= ic;
            }
            A1T[q+0][e] = v.x; A1T[q+1][e] = v.y;
            A1T[q+2][e] = v.z; A1T[q+3][e] = v.w;
        }
        #pragma unroll
        for (int p = 0; p < 4; ++p) {
            const int idx = p*256 + tid;
            const int k   = idx >> 6;
            const int n   = (idx & 63) * 4;
            *(float4*)&Bt[k][n] = *(const float4*)&W1[(size_t)(k0+k)*HID + n];
        }
        __syncthreads();
        #pragma unroll
        for (int kk = 0; kk < 16; ++kk) {
            const float4 b  = *(const float4*)&Bt[kk][c0];
            const float4 a0 = *(const float4*)&A1T[kk][r0];
            const float4 a1 = *(const float4*)&A1T[kk][r0+4];
            const float a[8] = {a0.x,a0.y,a0.z,a0.w,a1.x,a1.y,a1.z,a1.w};
            #pragma unroll
            for (int i = 0; i < 8; ++i) {
                acc[i][0] = fmaf(a[i], b.x, acc[i][0]);
                acc[i][1] = fmaf(a[i], b.y, acc[i][1]);
                acc[i][2] = fmaf(a[i], b.z, acc[i][2]);
                acc[i][3] = fmaf(a[i], b.w, acc[i][3]);
            }
        }
        __syncthreads();
    }
    {
        const float4 b1v = *(const float4*)&b1[c0];
        const float bb[4] = {b1v.x, b1v.y, b1v.z, b1v.w};
        #pragma unroll
        for (int j = 0; j < 4; ++j) {
            const int k = c0 + j;
            #pragma unroll
            for (int i = 0; i < 8; ++i) {
                const float x = acc[i][j] + bb[j];
                A2T[k][SWZ(k, r0+i)] = silu_f(x);
                acc[i][j] = 0.0f;
            }
        }
    }
    __syncthreads();
    for (int k0 = 0; k0 < HID; k0 += 16) {
        #pragma unroll
        for (int p = 0; p < 4; ++p) {
            const int idx = p*256 + tid;
            const int k   = idx >> 6;
            const int n   = (idx & 63) * 4;
            *(float4*)&Bt[k][n] = *(const float4*)&W2[(size_t)(k0+k)*HID + n];
        }
        __syncthreads();
        #pragma unroll
        for (int kk = 0; kk < 16; ++kk) {
            const int K = k0 + kk;
            const float4 b  = *(const float4*)&Bt[kk][c0];
            const float4 a0 = *(const float4*)&A2T[K][SWZ(K, r0)];
            const float4 a1 = *(const float4*)&A2T[K][SWZ(K, r0+4)];
            const float a[8] = {a0.x,a0.y,a0.z,a0.w,a1.x,a1.y,a1.z,a1.w};
            #pragma unroll
            for (int i = 0; i < 8; ++i) {
                acc[i][0] = fmaf(a[i], b.x, acc[i][0]);
                acc[i][1] = fmaf(a[i], b.y, acc[i][1]);
                acc[i][2] = fmaf(a[i], b.z, acc[i][2]);
                acc[i][3] = fmaf(a[i], b.w, acc[i][3]);
            }
        }
        __syncthreads();
    }
    {
        const float4 b2v = *(const float4*)&b2[c0];
        const float bb[4] = {b2v.x, b2v.y, b2v.z, b2v.w};
        float4 hv[8];
        #pragma unroll
        for (int i = 0; i < 8; ++i) {
            hv[i] = *(const float4*)&h[(size_t)(n0+r0+i)*HID + c0];
            acc[i][0] = hv[i].x + acc[i][0] + bb[0];
            acc[i][1] = hv[i].y + acc[i][1] + bb[1];
            acc[i][2] = hv[i].z + acc[i][2] + bb[2];
            acc[i][3] = hv[i].w + acc[i][3] + bb[3];
        }
        float s1[8], s2[8];
        #pragma unroll
        for (int i = 0; i < 8; ++i) {
            s1[i] = acc[i][0] + acc[i][1] + acc[i][2] + acc[i][3];
            s2[i] = acc[i][0]*acc[i][0] + acc[i][1]*acc[i][1]
                  + acc[i][2]*acc[i][2] + acc[i][3]*acc[i][3];
        }
        #pragma unroll
        for (int off = 32; off >= 1; off >>= 1) {
            #pragma unroll
            for (int i = 0; i < 8; ++i) {
                s1[i] += __shfl_xor(s1[i], off, 64);
                s2[i] += __shfl_xor(s2[i], off, 64);
            }
        }
        const float4 gv = *(const float4*)&lng[c0];
        const float4 bv = *(const float4*)&lnb[c0];
        const float g[4] = {gv.x, gv.y, gv.z, gv.w};
        const float bb2[4] = {bv.x, bv.y, bv.z, bv.w};
        #pragma unroll
        for (int i = 0; i < 8; ++i) {
            const int n = n0 + r0 + i;
            const bool lig = (ntype[n] == 1);
            float4 y;
            if (lig) {
                const float mu  = s1[i] * (1.0f/256.0f);
                const float var = s2[i] * (1.0f/256.0f) - mu*mu;
                const float rs  = rsqrtf(var + 1e-5f);
                y.x = (acc[i][0] - mu) * rs * g[0] + bb2[0];
                y.y = (acc[i][1] - mu) * rs * g[1] + bb2[1];
                y.z = (acc[i][2] - mu) * rs * g[2] + bb2[2];
                y.w = (acc[i][3] - mu) * rs * g[3] + bb2[3];
            } else {
                y = hv[i];
            }
            *(float4*)&out[(size_t)n*HID + c0] = y;
        }
    }
}

// ===========================================================================
extern "C" void kernel_launch(void* const* d_in, const int* in_sizes, int n_in,
                              void* d_out, int out_size, void* d_ws, size_t ws_size,
                              hipStream_t stream) {
    (void)in_sizes; (void)n_in; (void)out_size;
    const float* h    = (const float*)d_in[0];
    const float* pos  = (const float*)d_in[1];
    const int*   ei   = (const int*)  d_in[2];
    const int*   et   = (const int*)  d_in[3];
    const int*   nt   = (const int*)  d_in[4];
    const float* emb  = (const float*)d_in[5];
    const float* W1m  = (const float*)d_in[6];
    const float* b1m  = (const float*)d_in[7];
    const float* W2m  = (const float*)d_in[8];
    const float* b2m  = (const float*)d_in[9];
    const float* W1u  = (const float*)d_in[10];
    const float* b1u  = (const float*)d_in[11];
    const float* W2u  = (const float*)d_in[12];
    const float* b2u  = (const float*)d_in[13];
    const float* lng  = (const float*)d_in[14];
    const float* lnb  = (const float*)d_in[15];
    float* out = (float*)d_out;

    // workspace layout (512B-aligned segments)
    size_t o = 0;
    auto al = [&](size_t b) { size_t r = o; o = (o + b + 511) & ~(size_t)511; return r; };
    const size_t o_seg  = al((size_t)NN * HID * 4);
    const size_t o_cnt  = al((size_t)NN * 4);
    const size_t o_zend = o;                       // memset range [0, o_zend)
    const size_t o_hpl  = al((size_t)2 * NN * HID * 2);
    const size_t o_emb  = al((size_t)2 * 2 * HID * 2);
    const size_t o_w1t  = al((size_t)2 * 256 * 544 * 2);
    const size_t o_w2t  = al((size_t)2 * 256 * 256 * 2);
    const size_t o_w1ut = al((size_t)2 * 256 * 512 * 2);
    const size_t o_w2ut = al((size_t)2 * 256 * 256 * 2);
    const size_t o_T    = al((size_t)2 * 256 * 4);
    const size_t o_mipl = al((size_t)2 * NN * HID * 2);
    const size_t o_upl  = al((size_t)NN * HID * 2);
    const size_t o_mhi  = al((size_t)EE * HID * 2);
    const size_t need = o;

    char* ws = (char*)d_ws;
    float* seg = (float*)(ws + o_seg);
    float* cnt = (float*)(ws + o_cnt);

    if (ws_size >= need) {
        short* hpl   = (short*)(ws + o_hpl);
        short* embpl = (short*)(ws + o_emb);
        short* w1t   = (short*)(ws + o_w1t);
        short* w2t   = (short*)(ws + o_w2t);
        short* w1ut  = (short*)(ws + o_w1ut);
        short* w2ut  = (short*)(ws + o_w2ut);
        float* T     = (float*)(ws + o_T);
        short* mipl  = (short*)(ws + o_mipl);
        short* upl   = (short*)(ws + o_upl);
        short* mhi   = (short*)(ws + o_mhi);

        hipMemsetAsync(d_ws, 0, o_zend, stream);
        prep_all<<<PREP_TOTAL / 256, 256, 0, stream>>>(
            h, emb, W1m, W2m, W1u, W2u, hpl, embpl, w1t, w2t, w1ut, w2ut);
        tprep<<<1, 512, 0, stream>>>(W1m, b1m, emb, T);
        edge_mlp1<<<EE / 256, 512, 0, stream>>>(
            hpl, w1t, T, pos, ei, et, mhi, cnt);
        edge_mlp2<<<dim3(EE / 128, 2), 512, 0, stream>>>(mhi, w2t, b2m, ei, seg);
        mi_prep<<<(NN * HID) / 256, 256, 0, stream>>>(seg, cnt, mipl);
        const int nb = (NN + 127) / 128;
        node_mlp1<<<nb, 512, 0, stream>>>(hpl, mipl, w1ut, b1u, upl);
        node_mlp2<<<nb, 512, 0, stream>>>(upl, w2ut, b2u, h, nt, lng, lnb, out);
    } else {
        // fp32 fallback (round-1 kernels)
        hipMemsetAsync(d_ws, 0, ((size_t)NN * HID + NN) * sizeof(float), stream);
        float* seg0 = (float*)d_ws;
        float* cnt0 = seg0 + (size_t)NN * HID;
        edge_fp32<<<EE / 32, 256, 0, stream>>>(h, pos, ei, et, emb,
                                               W1m, b1m, W2m, b2m, seg0, cnt0);
        node_fp32<<<NN / 32, 256, 0, stream>>>(h, seg0, cnt0, nt,
                                               W1u, b1u, W2u, b2u, lng, lnb, out);
    }
}

// Round 7
// 837.788 us; speedup vs baseline: 3.5759x; 1.0413x over previous
//
#include <hip/hip_runtime.h>
#include <hip/hip_fp16.h>
#include <math.h>

#define NN   20000
#define EE   320000
#define HID  256
#define GAMMA_C ((31.0f/6.0f)*(31.0f/6.0f))   // 1/step^2, step = 6/31

typedef __attribute__((ext_vector_type(8)))  short    short8;   // 8 bf16 bits
typedef __attribute__((ext_vector_type(8)))  _Float16 half8;    // 8 fp16
typedef __attribute__((ext_vector_type(16))) float    f32x16;

__device__ __forceinline__ float silu_f(float x) {
    return x / (1.0f + __expf(-x));
}

// fp32 -> bf16 RNE bits
__device__ __forceinline__ short bf_hi(float x) {
    unsigned u = __float_as_uint(x);
    return (short)((u + 0x7fffu + ((u >> 16) & 1u)) >> 16);
}
__device__ __forceinline__ float bf_tof(short b) {
    return __uint_as_float(((unsigned)(unsigned short)b) << 16);
}
__device__ __forceinline__ void cvt_bf16_pair(float x, short* hi, short* lo) {
    short h = bf_hi(x);
    *hi = h;
    *lo = bf_hi(x - bf_tof(h));
}
__device__ __forceinline__ void cvt_f16_pair(float x, short* hi, short* lo) {
    __half h = __float2half_rn(x);
    *hi = (short)__half_as_ushort(h);
    *lo = (short)__half_as_ushort(__float2half_rn(x - __half2float(h)));
}
__device__ __forceinline__ short f16_bits(float x) {
    return (short)__half_as_ushort(__float2half_rn(x));
}

// async global->LDS, 16B per lane; LDS dest = uniform base + lane*16
typedef __attribute__((address_space(1))) const void GV;
typedef __attribute__((address_space(3))) void LV;
__device__ __forceinline__ void gll16(const void* g, void* l) {
    __builtin_amdgcn_global_load_lds((GV*)g, (LV*)l, 16, 0, 0);
}

// 128B rows = 8 slots of 16B; physical slot = sg ^ (row&7) (involution on
// both stage-source and read side — rule #21).
__device__ __forceinline__ short8 ldsfrag(const short* t, int row, int sg) {
    int s = sg ^ (row & 7);
    return *(const short8*)&t[row * 64 + s * 8];
}
// 64B rows = 4 slots of 16B; slot = sg ^ (row&3)
__device__ __forceinline__ half8 ldsfragh32(const short* t, int row, int sg) {
    int s = sg ^ (row & 3);
    return *(const half8*)&t[row * 32 + s * 8];
}
__device__ __forceinline__ half8 ldsfragh(const short* t, int row, int sg) {
    int s = sg ^ (row & 7);
    return *(const half8*)&t[row * 64 + s * 8];
}

// ---------------------------------------------------------------------------
// prep: fp32 -> split planes.  bf16 pairs: h, emb, W1m^T(folded), W1u^T.
//       f16 pairs: W2m^T, W2u^T.
// w1t layout: [256 cols][544 k'] where k'<512 -> orig k (src/dst halves),
//             k'>=512 -> orig k+256 (RBF rows 768..799). emb rows folded out.
// ---------------------------------------------------------------------------
#define S0 (NN*HID)     // h        5,120,000
#define S1 (2*HID)      // emb      512
#define S2 (256*544)    // W1t      139,264
#define S3 (256*256)    // W2t      65,536
#define S4 (256*512)    // W1ut     131,072
#define S5 (256*256)    // W2ut     65,536
#define PREP_TOTAL (S0+S1+S2+S3+S4+S5)   // 5,521,920 = 21570*256

__global__ __launch_bounds__(256) void prep_all(
    const float* __restrict__ h, const float* __restrict__ emb,
    const float* __restrict__ W1m, const float* __restrict__ W2m,
    const float* __restrict__ W1u, const float* __restrict__ W2u,
    short* __restrict__ hpl, short* __restrict__ embpl,
    short* __restrict__ w1t, short* __restrict__ w2t,
    short* __restrict__ w1ut, short* __restrict__ w2ut)
{
    int i = blockIdx.x * 256 + threadIdx.x;
    float x; short *hi, *lo; int o; int f16 = 0;
    if (i < S0)              { x = h[i];   hi = hpl;   lo = hpl + S0;   o = i; }
    else if ((i -= S0) < S1) { x = emb[i]; hi = embpl; lo = embpl + S1; o = i; }
    else if ((i -= S1) < S2) { int n = i / 544, k = i - n * 544;
                               int ok = (k < 512) ? k : (k + 256);
                               x = W1m[ok * 256 + n]; hi = w1t; lo = w1t + S2; o = i; }
    else if ((i -= S2) < S3) { int n = i >> 8, k = i & 255;
                               x = W2m[k * 256 + n]; hi = w2t; lo = w2t + S3; o = i; f16 = 1; }
    else if ((i -= S3) < S4) { int n = i >> 9, k = i & 511;
                               x = W1u[k * 256 + n]; hi = w1ut; lo = w1ut + S4; o = i; }
    else if ((i -= S4) < S5) { int n = i >> 8, k = i & 255;
                               x = W2u[k * 256 + n]; hi = w2ut; lo = w2ut + S5; o = i; f16 = 1; }
    else return;
    short hb, lb;
    if (f16) cvt_f16_pair(x, &hb, &lb); else cvt_bf16_pair(x, &hb, &lb);
    hi[o] = hb; lo[o] = lb;
}

// ---------------------------------------------------------------------------
// tprep: T[e][n] = b1m[n] + sum_k emb[e][k] * W1m[512+k][n]   (exact fp32)
// grid = 2 blocks (one per edge type), emb row staged in LDS.
// ---------------------------------------------------------------------------
__global__ __launch_bounds__(256) void tprep(
    const float* __restrict__ W1m, const float* __restrict__ b1,
    const float* __restrict__ emb, float* __restrict__ T)
{
    __shared__ float er[256];
    const int e = blockIdx.x, n = threadIdx.x;
    er[n] = emb[e * 256 + n];
    __syncthreads();
    float s = b1[n];
    for (int k = 0; k < 256; ++k)
        s = fmaf(er[k], W1m[(512 + k) * 256 + n], s);
    T[e * 256 + n] = s;
}

// ---------------------------------------------------------------------------
// edge_mlp1 v4: m = silu(hs@W1a + hd@W1b + radial@W1c + T[et]) -> fp16 plane.
// ROUND-4 measured-best structure (37.4% MfmaUtil, 43% occupancy) + K=544
// fold. Block = 128 edges x 128 cols (grid.y=2), 512 thr, 8 waves (2mh x
// 4ns), wave tile 64x32 -> acc[2] (32 AGPR). launch_bounds(512,4) -> 2
// blocks/CU (67.5 KB LDS). 2-deep dbuf, stage-ahead, __syncthreads drain.
// K=544 in 17 chunks of 32 (chunk 16 = RBF via swizzled ds_write).
// ---------------------------------------------------------------------------
__global__ __launch_bounds__(512, 4) void edge_mlp1(
    const short* __restrict__ hpl, const short* __restrict__ w1t,
    const float* __restrict__ Ttab, const float* __restrict__ pos,
    const int* __restrict__ ei, const int* __restrict__ etype,
    short* __restrict__ mhi, float* __restrict__ cnt)
{
    __shared__ __align__(16) short At[2][128 * 64];   // 2 x 16 KB
    __shared__ __align__(16) short Bt[2][128 * 64];   // 2 x 16 KB
    __shared__ int srcS[128], dstS[128], etS[128];
    __shared__ float distS[128];

    const int tid = threadIdx.x, l = tid & 63, w = tid >> 6;
    const int e0 = blockIdx.x * 128;
    const int cb = blockIdx.y;                 // col-block: cols cb*128..+127
    const int mh = w >> 2, ns = w & 3;

    if (tid < 128) {
        int s = ei[e0 + tid], d = ei[EE + e0 + tid];
        srcS[tid] = s; dstS[tid] = d; etS[tid] = etype[e0 + tid];
        float dx = pos[3*s]   - pos[3*d];
        float dy = pos[3*s+1] - pos[3*d+1];
        float dz = pos[3*s+2] - pos[3*d+2];
        distS[tid] = sqrtf(dx*dx + dy*dy + dz*dz);
        if (cb == 0) atomicAdd(&cnt[d], 1.0f);
    }
    __syncthreads();

    auto stageA = [&](int buf, int c) {
        if (c < 16) {
            #pragma unroll
            for (int jj = 0; jj < 2; ++jj) {
                int j = w * 2 + jj;
                int row = j * 8 + (l >> 3), s = l & 7;
                int sg = s ^ (row & 7);
                int hl = sg >> 2, q = sg & 3;
                const short* gp = (c < 8)
                    ? hpl + (size_t)hl * (NN*HID) + (size_t)srcS[row] * HID + c*32 + q*8
                    : hpl + (size_t)hl * (NN*HID) + (size_t)dstS[row] * HID + (c-8)*32 + q*8;
                gll16(gp, &At[buf][j * 512]);
            }
        } else {
            // RBF chunk (k' 512..543): compute + swizzled ds_write
            #pragma unroll
            for (int jj = 0; jj < 2; ++jj) {
                int it = tid * 2 + jj;
                int row = it >> 3, s = it & 7;
                int sg = s ^ (row & 7);
                int hl = sg >> 2, q = sg & 3;
                float d = distS[row];
                short8 v;
                #pragma unroll
                for (int k8 = 0; k8 < 8; ++k8) {
                    float cen = (float)(q * 8 + k8) * (6.0f / 31.0f);
                    float t = d - cen;
                    float f = __expf(-GAMMA_C * t * t);
                    short hb = bf_hi(f);
                    v[k8] = hl ? bf_hi(f - bf_tof(hb)) : hb;
                }
                *(short8*)&At[buf][row * 64 + s * 8] = v;
            }
        }
    };
    auto stageB = [&](int buf, int c) {
        #pragma unroll
        for (int jj = 0; jj < 2; ++jj) {
            int j = w * 2 + jj;
            int n = j * 8 + (l >> 3), s = l & 7;
            int sg = s ^ (n & 7);
            int hl = sg >> 2, q = sg & 3;
            const short* gp = w1t + (size_t)hl * (256*544)
                            + (size_t)(cb*128 + n) * 544 + c*32 + q*8;
            gll16(gp, &Bt[buf][j * 512]);
        }
    };

    f32x16 acc[2];
    #pragma unroll
    for (int a = 0; a < 2; ++a)
        #pragma unroll
        for (int q = 0; q < 16; ++q) acc[a][q] = 0.0f;

    // prologue: stage chunk 0
    stageA(0, 0); stageB(0, 0);
    __syncthreads();

    int cur = 0;
    for (int c = 0; c < 17; ++c) {
        if (c < 16) { stageA(cur ^ 1, c + 1); stageB(cur ^ 1, c + 1); }
        #pragma unroll
        for (int t2 = 0; t2 < 2; ++t2) {
            short8 aF[2][2], bF[2];
            #pragma unroll
            for (int mf = 0; mf < 2; ++mf) {
                int row = mh * 64 + mf * 32 + (l & 31);
                #pragma unroll
                for (int hl = 0; hl < 2; ++hl)
                    aF[mf][hl] = ldsfrag(&At[cur][0], row, hl * 4 + t2 * 2 + (l >> 5));
            }
            {
                int n = ns * 32 + (l & 31);
                #pragma unroll
                for (int hl = 0; hl < 2; ++hl)
                    bF[hl] = ldsfrag(&Bt[cur][0], n, hl * 4 + t2 * 2 + (l >> 5));
            }
            #pragma unroll
            for (int mf = 0; mf < 2; ++mf) {
                acc[mf] = __builtin_amdgcn_mfma_f32_32x32x16_bf16(aF[mf][0], bF[0], acc[mf], 0, 0, 0);
                acc[mf] = __builtin_amdgcn_mfma_f32_32x32x16_bf16(aF[mf][0], bF[1], acc[mf], 0, 0, 0);
                acc[mf] = __builtin_amdgcn_mfma_f32_32x32x16_bf16(aF[mf][1], bF[0], acc[mf], 0, 0, 0);
            }
        }
        __syncthreads();   // drains vmcnt (c+1 stage landed) + lgkm; swap
        cur ^= 1;
    }

    // epilogue: + T[et][col], silu -> fp16 m plane
    {
        int col = cb * 128 + ns * 32 + (l & 31);
        #pragma unroll
        for (int mf = 0; mf < 2; ++mf)
            #pragma unroll
            for (int r = 0; r < 16; ++r) {
                int row = mh * 64 + mf * 32 + (r & 3) + 8 * (r >> 2) + 4 * (l >> 5);
                float tv = Ttab[etS[row] * 256 + col];
                float v = silu_f(acc[mf][r] + tv);
                mhi[(size_t)(e0 + row) * HID + col] = f16_bits(v);
            }
    }
}

// ---------------------------------------------------------------------------
// edge_mlp2: m_ij = silu(m @ W2m + b2m); atomicAdd into seg[dst].
// (round-4/5 passing version, unchanged)
// ---------------------------------------------------------------------------
__global__ __launch_bounds__(512, 4) void edge_mlp2(
    const short* __restrict__ mhi, const short* __restrict__ w2t,
    const float* __restrict__ b2, const int* __restrict__ ei,
    float* __restrict__ seg)
{
    __shared__ __align__(16) short Ah[2][128 * 32];   // 2 x 8 KB
    __shared__ __align__(16) short Bh[2][128 * 32];
    __shared__ __align__(16) short Bl[2][128 * 32];
    __shared__ int dstS[128];
    const int tid = threadIdx.x, l = tid & 63, w = tid >> 6;
    const int e0 = blockIdx.x * 128;
    const int cb = blockIdx.y;
    const int mh = w >> 2, ns = w & 3;
    if (tid < 128) dstS[tid] = ei[EE + e0 + tid];
    __syncthreads();

    auto stageA = [&](int buf, int c) {
        int row = w * 16 + (l >> 2), s = l & 3;
        int sg = s ^ (row & 3);
        gll16(mhi + (size_t)(e0 + row) * HID + c * 32 + sg * 8, &Ah[buf][w * 512]);
    };
    auto stageB = [&](int buf, int c) {
        #pragma unroll
        for (int jj = 0; jj < 2; ++jj) {
            int j = w * 2 + jj;
            int hf = j >> 3, jn = j & 7;
            int n = jn * 16 + (l >> 2), s = l & 3;
            int sg = s ^ (n & 3);
            const short* gp = w2t + (size_t)hf * (256*256)
                            + (size_t)(cb*128 + n) * HID + c * 32 + sg * 8;
            gll16(gp, hf ? &Bl[buf][jn * 512] : &Bh[buf][jn * 512]);
        }
    };

    f32x16 acc[2];
    #pragma unroll
    for (int a = 0; a < 2; ++a)
        #pragma unroll
        for (int q = 0; q < 16; ++q) acc[a][q] = 0.0f;

    stageA(0, 0); stageB(0, 0);
    __syncthreads();

    int cur = 0;
    for (int c = 0; c < 8; ++c) {
        if (c < 7) { stageA(cur ^ 1, c + 1); stageB(cur ^ 1, c + 1); }
        #pragma unroll
        for (int t2 = 0; t2 < 2; ++t2) {
            int sg = t2 * 2 + (l >> 5);
            half8 aF[2], bH, bL;
            #pragma unroll
            for (int mf = 0; mf < 2; ++mf)
                aF[mf] = ldsfragh32(&Ah[cur][0], mh * 64 + mf * 32 + (l & 31), sg);
            {
                int n = ns * 32 + (l & 31);
                bH = ldsfragh32(&Bh[cur][0], n, sg);
                bL = ldsfragh32(&Bl[cur][0], n, sg);
            }
            #pragma unroll
            for (int mf = 0; mf < 2; ++mf) {
                acc[mf] = __builtin_amdgcn_mfma_f32_32x32x16_f16(aF[mf], bH, acc[mf], 0, 0, 0);
                acc[mf] = __builtin_amdgcn_mfma_f32_32x32x16_f16(aF[mf], bL, acc[mf], 0, 0, 0);
            }
        }
        __syncthreads();
        cur ^= 1;
    }

    {
        int col = cb * 128 + ns * 32 + (l & 31);
        float bb = b2[col];
        #pragma unroll
        for (int mf = 0; mf < 2; ++mf)
            #pragma unroll
            for (int r = 0; r < 16; ++r) {
                int row = mh * 64 + mf * 32 + (r & 3) + 8 * (r >> 2) + 4 * (l >> 5);
                float v = silu_f(acc[mf][r] + bb);
                atomicAdd(&seg[(size_t)dstS[row] * HID + col], v);
            }
    }
}

// ---------------------------------------------------------------------------
// mi_prep: m_i = seg / max(cnt,1) -> bf16 hi/lo planes
// ---------------------------------------------------------------------------
__global__ __launch_bounds__(256) void mi_prep(
    const float* __restrict__ seg, const float* __restrict__ cnt,
    short* __restrict__ mipl)
{
    int i = blockIdx.x * 256 + threadIdx.x;
    int row = i >> 8;
    float v = seg[i] / fmaxf(cnt[row], 1.0f);
    short hb, lb;
    cvt_bf16_pair(v, &hb, &lb);
    mipl[i] = hb;
    mipl[(size_t)NN * HID + i] = lb;
}

// ---------------------------------------------------------------------------
// node_mlp1: u = silu([h, m_i] @ W1u + b1u) -> fp16 plane. K=512, 16 chunks.
// (round-3/4/5 passing version, unchanged)
// ---------------------------------------------------------------------------
__global__ __launch_bounds__(512) void node_mlp1(
    const short* __restrict__ hpl, const short* __restrict__ mipl,
    const short* __restrict__ w1ut, const float* __restrict__ b1,
    short* __restrict__ u)
{
    __shared__ __align__(16) short At[128 * 64];
    __shared__ __align__(16) short Bt[256 * 64];
    const int tid = threadIdx.x, l = tid & 63, w = tid >> 6;
    const int n0 = blockIdx.x * 128;
    const int mh = w >> 2, ns = w & 3;

    f32x16 acc[2][2];
    #pragma unroll
    for (int a = 0; a < 2; ++a)
        #pragma unroll
        for (int b = 0; b < 2; ++b)
            #pragma unroll
            for (int q = 0; q < 16; ++q) acc[a][b][q] = 0.0f;

    for (int c = 0; c < 16; ++c) {
        #pragma unroll
        for (int jj = 0; jj < 2; ++jj) {
            int j = w * 2 + jj;
            int row = j * 8 + (l >> 3), s = l & 7;
            int sg = s ^ (row & 7);
            int hl = sg >> 2, q = sg & 3;
            int node = min(n0 + row, NN - 1);
            const short* gp = (c < 8)
                ? hpl  + (size_t)hl * (NN*HID) + (size_t)node * HID + c * 32 + q * 8
                : mipl + (size_t)hl * (NN*HID) + (size_t)node * HID + (c - 8) * 32 + q * 8;
            gll16(gp, &At[j * 512]);
        }
        #pragma unroll
        for (int jj = 0; jj < 4; ++jj) {
            int j = w * 4 + jj;
            int n = j * 8 + (l >> 3), s = l & 7;
            int sg = s ^ (n & 7);
            int hl = sg >> 2, q = sg & 3;
            const short* gp = w1ut + (size_t)hl * (256*512) + n * 512 + c * 32 + q * 8;
            gll16(gp, &Bt[j * 512]);
        }
        __syncthreads();
        #pragma unroll
        for (int t2 = 0; t2 < 2; ++t2) {
            short8 aF[2][2], bF[2][2];
            #pragma unroll
            for (int mf = 0; mf < 2; ++mf) {
                int row = mh * 64 + mf * 32 + (l & 31);
                #pragma unroll
                for (int hl = 0; hl < 2; ++hl)
                    aF[mf][hl] = ldsfrag(At, row, hl * 4 + t2 * 2 + (l >> 5));
            }
            #pragma unroll
            for (int nf = 0; nf < 2; ++nf) {
                int n = ns * 64 + nf * 32 + (l & 31);
                #pragma unroll
                for (int hl = 0; hl < 2; ++hl)
                    bF[nf][hl] = ldsfrag(Bt, n, hl * 4 + t2 * 2 + (l >> 5));
            }
            #pragma unroll
            for (int mf = 0; mf < 2; ++mf)
                #pragma unroll
                for (int nf = 0; nf < 2; ++nf) {
                    acc[mf][nf] = __builtin_amdgcn_mfma_f32_32x32x16_bf16(aF[mf][0], bF[nf][0], acc[mf][nf], 0, 0, 0);
                    acc[mf][nf] = __builtin_amdgcn_mfma_f32_32x32x16_bf16(aF[mf][0], bF[nf][1], acc[mf][nf], 0, 0, 0);
                    acc[mf][nf] = __builtin_amdgcn_mfma_f32_32x32x16_bf16(aF[mf][1], bF[nf][0], acc[mf][nf], 0, 0, 0);
                }
        }
        __syncthreads();
    }
    #pragma unroll
    for (int nf = 0; nf < 2; ++nf) {
        int col = ns * 64 + nf * 32 + (l & 31);
        float bb = b1[col];
        #pragma unroll
        for (int mf = 0; mf < 2; ++mf)
            #pragma unroll
            for (int r = 0; r < 16; ++r) {
                int row = mh * 64 + mf * 32 + (r & 3) + 8 * (r >> 2) + 4 * (l >> 5);
                if (n0 + row < NN) {
                    float v = silu_f(acc[mf][nf][r] + bb);
                    u[(size_t)(n0 + row) * HID + col] = f16_bits(v);
                }
            }
    }
}

// ---------------------------------------------------------------------------
// node_mlp2: upd = u @ W2u + b2u; out = lig ? LN(h+upd)*g+b : h
// (round-3/4/5 passing version, unchanged)
// ---------------------------------------------------------------------------
__global__ __launch_bounds__(512) void node_mlp2(
    const short* __restrict__ u, const short* __restrict__ w2ut,
    const float* __restrict__ b2, const float* __restrict__ h,
    const int* __restrict__ ntype, const float* __restrict__ lng,
    const float* __restrict__ lnb, float* __restrict__ out)
{
    __shared__ __align__(16) short Ah[128 * 64];
    __shared__ __align__(16) short Bh[256 * 64];
    __shared__ __align__(16) short Bl[256 * 64];
    __shared__ float red1[4][128], red2[4][128];
    __shared__ float muS[128], rsS[128];
    const int tid = threadIdx.x, l = tid & 63, w = tid >> 6;
    const int n0 = blockIdx.x * 128;
    const int mh = w >> 2, ns = w & 3;

    f32x16 acc[2][2];
    #pragma unroll
    for (int a = 0; a < 2; ++a)
        #pragma unroll
        for (int b = 0; b < 2; ++b)
            #pragma unroll
            for (int q = 0; q < 16; ++q) acc[a][b][q] = 0.0f;

    for (int c = 0; c < 4; ++c) {
        #pragma unroll
        for (int jj = 0; jj < 2; ++jj) {
            int j = w * 2 + jj;
            int row = j * 8 + (l >> 3), s = l & 7;
            int sg = s ^ (row & 7);
            int node = min(n0 + row, NN - 1);
            gll16(u + (size_t)node * HID + c * 64 + sg * 8, &Ah[j * 512]);
        }
        #pragma unroll
        for (int jj = 0; jj < 8; ++jj) {
            int j = w * 8 + jj;
            int hf = j >> 5;
            int n = (j & 31) * 8 + (l >> 3), s = l & 7;
            int sg = s ^ (n & 7);
            const short* gp = w2ut + (size_t)hf * (256*256) + n * HID + c * 64 + sg * 8;
            gll16(gp, hf ? &Bl[(j & 31) * 512] : &Bh[(j & 31) * 512]);
        }
        __syncthreads();
        #pragma unroll
        for (int t2 = 0; t2 < 4; ++t2) {
            int sg = t2 * 2 + (l >> 5);
            half8 aF[2], bH[2], bL[2];
            #pragma unroll
            for (int mf = 0; mf < 2; ++mf)
                aF[mf] = ldsfragh(Ah, mh * 64 + mf * 32 + (l & 31), sg);
            #pragma unroll
            for (int nf = 0; nf < 2; ++nf) {
                int n = ns * 64 + nf * 32 + (l & 31);
                bH[nf] = ldsfragh(Bh, n, sg);
                bL[nf] = ldsfragh(Bl, n, sg);
            }
            #pragma unroll
            for (int mf = 0; mf < 2; ++mf)
                #pragma unroll
                for (int nf = 0; nf < 2; ++nf) {
                    acc[mf][nf] = __builtin_amdgcn_mfma_f32_32x32x16_f16(aF[mf], bH[nf], acc[mf][nf], 0, 0, 0);
                    acc[mf][nf] = __builtin_amdgcn_mfma_f32_32x32x16_f16(aF[mf], bL[nf], acc[mf][nf], 0, 0, 0);
                }
        }
        __syncthreads();
    }

    #pragma unroll
    for (int nf = 0; nf < 2; ++nf) {
        int col = ns * 64 + nf * 32 + (l & 31);
        float bb = b2[col];
        #pragma unroll
        for (int mf = 0; mf < 2; ++mf)
            #pragma unroll
            for (int r = 0; r < 16; ++r) {
                int row = mh * 64 + mf * 32 + (r & 3) + 8 * (r >> 2) + 4 * (l >> 5);
                int node = min(n0 + row, NN - 1);
                acc[mf][nf][r] += bb + h[(size_t)node * HID + col];
            }
    }
    #pragma unroll
    for (int mf = 0; mf < 2; ++mf)
        #pragma unroll
        for (int r = 0; r < 16; ++r) {
            float v1 = acc[mf][0][r] + acc[mf][1][r];
            float v2 = acc[mf][0][r]*acc[mf][0][r] + acc[mf][1][r]*acc[mf][1][r];
            #pragma unroll
            for (int off = 16; off >= 1; off >>= 1) {
                v1 += __shfl_xor(v1, off, 64);
                v2 += __shfl_xor(v2, off, 64);
            }
            if ((l & 31) == 0) {
                int row = mh * 64 + mf * 32 + (r & 3) + 8 * (r >> 2) + 4 * (l >> 5);
                red1[ns][row] = v1; red2[ns][row] = v2;
            }
        }
    __syncthreads();
    if (tid < 128) {
        float s1 = red1[0][tid] + red1[1][tid] + red1[2][tid] + red1[3][tid];
        float s2 = red2[0][tid] + red2[1][tid] + red2[2][tid] + red2[3][tid];
        float mu = s1 * (1.0f / 256.0f);
        float var = s2 * (1.0f / 256.0f) - mu * mu;
        muS[tid] = mu;
        rsS[tid] = rsqrtf(var + 1e-5f);
    }
    __syncthreads();
    #pragma unroll
    for (int nf = 0; nf < 2; ++nf) {
        int col = ns * 64 + nf * 32 + (l & 31);
        float g = lng[col], bt = lnb[col];
        #pragma unroll
        for (int mf = 0; mf < 2; ++mf)
            #pragma unroll
            for (int r = 0; r < 16; ++r) {
                int row = mh * 64 + mf * 32 + (r & 3) + 8 * (r >> 2) + 4 * (l >> 5);
                int node = n0 + row;
                if (node < NN) {
                    float y;
                    if (ntype[node] == 1)
                        y = (acc[mf][nf][r] - muS[row]) * rsS[row] * g + bt;
                    else
                        y = h[(size_t)node * HID + col];
                    out[(size_t)node * HID + col] = y;
                }
            }
    }
}

// ===========================================================================
// fp32 fallback path (proven correct in round 1) — used if ws_size too small
// ===========================================================================
#define SWZ(k, e) ((e) ^ ((((k) >> 2) & 7) << 2))

__global__ __launch_bounds__(256) void edge_fp32(
    const float* __restrict__ h, const float* __restrict__ pos,
    const int* __restrict__ ei, const int* __restrict__ etype,
    const float* __restrict__ emb,
    const float* __restrict__ W1, const float* __restrict__ b1,
    const float* __restrict__ W2, const float* __restrict__ b2,
    float* __restrict__ seg, float* __restrict__ cnt)
{
    __shared__ float A1T[16][32];
    __shared__ float Bt[16][256];
    __shared__ float A2T[256][32];
    __shared__ float distS[32];
    __shared__ int   srcS[32], dstS[32], etS[32];
    const int tid = threadIdx.x;
    const int e0  = blockIdx.x * 32;
    if (tid < 32) {
        const int e = e0 + tid;
        const int s = ei[e];
        const int d = ei[EE + e];
        srcS[tid] = s; dstS[tid] = d; etS[tid] = etype[e];
        const float dx = pos[3*s+0] - pos[3*d+0];
        const float dy = pos[3*s+1] - pos[3*d+1];
        const float dz = pos[3*s+2] - pos[3*d+2];
        distS[tid] = sqrtf(dx*dx + dy*dy + dz*dz);
        atomicAdd(&cnt[d], 1.0f);
    }
    __syncthreads();
    const int c0 = (tid & 63) * 4;
    const int r0 = (tid >> 6) * 8;
    float acc[8][4];
    #pragma unroll
    for (int i = 0; i < 8; ++i)
        #pragma unroll
        for (int j = 0; j < 4; ++j) acc[i][j] = 0.0f;
    const float step  = 6.0f / 31.0f;
    for (int k0 = 0; k0 < 800; k0 += 16) {
        if (tid < 128) {
            const int e = tid >> 2;
            const int q = (tid & 3) * 4;
            const int k = k0 + q;
            float4 v;
            if (k < 256)       v = *(const float4*)&h[(size_t)srcS[e]*HID + k];
            else if (k < 512)  v = *(const float4*)&h[(size_t)dstS[e]*HID + (k - 256)];
            else if (k < 768)  v = *(const float4*)&emb[(size_t)etS[e]*HID + (k - 512)];
            else {
                const float de = distS[e];
                const float t0 = de - step*(float)(k-768);
                const float t1 = de - step*(float)(k-767);
                const float t2 = de - step*(float)(k-766);
                const float t3 = de - step*(float)(k-765);
                v = make_float4(__expf(-GAMMA_C*t0*t0), __expf(-GAMMA_C*t1*t1),
                                __expf(-GAMMA_C*t2*t2), __expf(-GAMMA_C*t3*t3));
            }
            A1T[q+0][e] = v.x; A1T[q+1][e] = v.y;
            A1T[q+2][e] = v.z; A1T[q+3][e] = v.w;
        }
        #pragma unroll
        for (int p = 0; p < 4; ++p) {
            const int idx = p*256 + tid;
            const int k   = idx >> 6;
            const int n   = (idx & 63) * 4;
            *(float4*)&Bt[k][n] = *(const float4*)&W1[(size_t)(k0+k)*HID + n];
        }
        __syncthreads();
        #pragma unroll
        for (int kk = 0; kk < 16; ++kk) {
            const float4 b  = *(const float4*)&Bt[kk][c0];
            const float4 a0 = *(const float4*)&A1T[kk][r0];
            const float4 a1 = *(const float4*)&A1T[kk][r0+4];
            const float a[8] = {a0.x,a0.y,a0.z,a0.w,a1.x,a1.y,a1.z,a1.w};
            #pragma unroll
            for (int i = 0; i < 8; ++i) {
                acc[i][0] = fmaf(a[i], b.x, acc[i][0]);
                acc[i][1] = fmaf(a[i], b.y, acc[i][1]);
                acc[i][2] = fmaf(a[i], b.z, acc[i][2]);
                acc[i][3] = fmaf(a[i], b.w, acc[i][3]);
            }
        }
        __syncthreads();
    }
    {
        const float4 b1v = *(const float4*)&b1[c0];
        const float bb[4] = {b1v.x, b1v.y, b1v.z, b1v.w};
        #pragma unroll
        for (int j = 0; j < 4; ++j) {
            const int k = c0 + j;
            #pragma unroll
            for (int i = 0; i < 8; ++i) {
                const float x = acc[i][j] + bb[j];
                A2T[k][SWZ(k, r0+i)] = silu_f(x);
                acc[i][j] = 0.0f;
            }
        }
    }
    __syncthreads();
    for (int k0 = 0; k0 < HID; k0 += 16) {
        #pragma unroll
        for (int p = 0; p < 4; ++p) {
            const int idx = p*256 + tid;
            const int k   = idx >> 6;
            const int n   = (idx & 63) * 4;
            *(float4*)&Bt[k][n] = *(const float4*)&W2[(size_t)(k0+k)*HID + n];
        }
        __syncthreads();
        #pragma unroll
        for (int kk = 0; kk < 16; ++kk) {
            const int K = k0 + kk;
            const float4 b  = *(const float4*)&Bt[kk][c0];
            const float4 a0 = *(const float4*)&A2T[K][SWZ(K, r0)];
            const float4 a1 = *(const float4*)&A2T[K][SWZ(K, r0+4)];
            const float a[8] = {a0.x,a0.y,a0.z,a0.w,a1.x,a1.y,a1.z,a1.w};
            #pragma unroll
            for (int i = 0; i < 8; ++i) {
                acc[i][0] = fmaf(a[i], b.x, acc[i][0]);
                acc[i][1] = fmaf(a[i], b.y, acc[i][1]);
                acc[i][2] = fmaf(a[i], b.z, acc[i][2]);
                acc[i][3] = fmaf(a[i], b.w, acc[i][3]);
            }
        }
        __syncthreads();
    }
    {
        const float4 b2v = *(const float4*)&b2[c0];
        const float bb[4] = {b2v.x, b2v.y, b2v.z, b2v.w};
        #pragma unroll
        for (int i = 0; i < 8; ++i) {
            const int d = dstS[r0 + i];
            float* outp = &seg[(size_t)d*HID + c0];
            #pragma unroll
            for (int j = 0; j < 4; ++j) {
                const float x = acc[i][j] + bb[j];
                atomicAdd(&outp[j], silu_f(x));
            }
        }
    }
}

__global__ __launch_bounds__(256) void node_fp32(
    const float* __restrict__ h, const float* __restrict__ seg,
    const float* __restrict__ cnt, const int* __restrict__ ntype,
    const float* __restrict__ W1, const float* __restrict__ b1,
    const float* __restrict__ W2, const float* __restrict__ b2,
    const float* __restrict__ lng, const float* __restrict__ lnb,
    float* __restrict__ out)
{
    __shared__ float A1T[16][32];
    __shared__ float Bt[16][256];
    __shared__ float A2T[256][32];
    __shared__ float invS[32];
    const int tid = threadIdx.x;
    const int n0  = blockIdx.x * 32;
    if (tid < 32) invS[tid] = 1.0f / fmaxf(cnt[n0 + tid], 1.0f);
    __syncthreads();
    const int c0 = (tid & 63) * 4;
    const int r0 = (tid >> 6) * 8;
    float acc[8][4];
    #pragma unroll
    for (int i = 0; i < 8; ++i)
        #pragma unroll
        for (int j = 0; j < 4; ++j) acc[i][j] = 0.0f;
    for (int k0 = 0; k0 < 512; k0 += 16) {
        if (tid < 128) {
            const int e = tid >> 2;
            const int q = (tid & 3) * 4;
            const int k = k0 + q;
            float4 v;
            if (k < 256) v = *(const float4*)&h[(size_t)(n0+e)*HID + k];
            else {
                v = *(const float4*)&seg[(size_t)(n0+e)*HID + (k - 256)];
                const float ic = invS[e];
                v.x *= ic; v.y *= ic; v.z *= ic; v.w *= ic;
            }
            A1T[q+0][e] = v.x; A1T[q+1][e] = v.y;
            A1T[q+2][e] = v.z; A1T[q+3][e] = v.w;
        }
        #pragma unroll
        for (int p = 0; p < 4; ++p) {
            const int idx = p*256 + tid;
            const int k   = idx >> 6;
            const int n   = (idx & 63) * 4;
            *(float4*)&Bt[k][n] = *(const float4*)&W1[(size_t)(k0+k)*HID + n];
        }
        __syncthreads();
        #pragma unroll
        for (int kk = 0; kk < 16; ++kk) {
            const float4 b  = *(const float4*)&Bt[kk][c0];
            const float4 a0 = *(const float4*)&A1T[kk][r0];
            const float4 a1 = *(const float4*)&A1T[kk][r0+4];
            const float a[8] = {a0.x,a0.y,a0.z,a0.w,a1.x,a1.y,a1.z,a1.w};
            #pragma unroll
            for (int i = 0; i < 8; ++i) {
                acc[i][0] = fmaf(a[i], b.x, acc[i][0]);
                acc[i][1] = fmaf(a[i], b.y, acc[i][1]);
                acc[i][2] = fmaf(a[i], b.z, acc[i][2]);
                acc[i][3] = fmaf(a[i], b.w, acc[i][3]);
            }
        }
        __syncthreads();
    }
    {
        const float4 b1v = *(const float4*)&b1[c0];
        const float bb[4] = {b1v.x, b1v.y, b1v.z, b1v.w};
        #pragma unroll
        for (int j = 0; j < 4; ++j) {
            const int k = c0 + j;
            #pragma unroll
            for (int i = 0; i < 8; ++i) {
                const float x = acc[i][j] + bb[j];
                A2T[k][SWZ(k, r0+i)] = silu_f(x);
                acc[i][j] = 0.0f;
            }
        }
    }
    __syncthreads();
    for (int k0 = 0; k0 < HID; k0 += 16) {
        #pragma unroll
        for (int p = 0; p < 4; ++p) {
            const int idx = p*256 + tid;
            const int k   = idx >> 6;
            const int n   = (idx & 63) * 4;
            *(float4*)&Bt[k][n] = *(const float4*)&W2[(size_t)(k0+k)*HID + n];
        }
        __syncthreads();
        #pragma unroll
        for (int kk = 0; kk < 16; ++kk) {
            const int K = k0 + kk;
            const float4 b  = *(const float4*)&Bt[kk][c0];
            const float4 a0 = *(const float4*)&A2T[K][SWZ(K, r0)];
            const float4 a1 = *(const float4*)&A2T[K][SWZ(K, r0+4)];
            const float a[8] = {a0.x,a0.y,a0.z,a0.w,a1.x,a1.y,a1.z,a1.w};
            #pragma unroll
            for (int i = 0; i < 8; ++i) {
                acc[i][0] = fmaf(a[i], b.x, acc[i][0]);
                acc[i][1] = fmaf(a[i], b.y, acc[i][1]);
                acc[i][2] = fmaf(a[i], b.z, acc[i][2]);
                acc[i][3] = fmaf(a[i], b.w, acc[i][3]);
            }
        }
        __syncthreads();
    }
    {
        const float4 b2v = *(const float4*)&b2[c0];
        const float bb[4] = {b2v.x, b2v.y, b2v.z, b2v.w};
        float4 hv[8];
        #pragma unroll
        for (int i = 0; i < 8; ++i) {
            hv[i] = *(const float4*)&h[(size_t)(n0+r0+i)*HID + c0];
            acc[i][0] = hv[i].x + acc[i][0] + bb[0];
            acc[i][1] = hv[i].y + acc[i][1] + bb[1];
            acc[i][2] = hv[i].z + acc[i][2] + bb[2];
            acc[i][3] = hv[i].w + acc[i][3] + bb[3];
        }
        float s1[8], s2[8];
        #pragma unroll
        for (int i = 0; i < 8; ++i) {
            s1[i] = acc[i][0] + acc[i][1] + acc[i][2] + acc[i][3];
            s2[i] = acc[i][0]*acc[i][0] + acc[i][1]*acc[i][1]
                  + acc[i][2]*acc[i][2] + acc[i][3]*acc[i][3];
        }
        #pragma unroll
        for (int off = 32; off >= 1; off >>= 1) {
            #pragma unroll
            for (int i = 0; i < 8; ++i) {
                s1[i] += __shfl_xor(s1[i], off, 64);
                s2[i] += __shfl_xor(s2[i], off, 64);
            }
        }
        const float4 gv = *(const float4*)&lng[c0];
        const float4 bv = *(const float4*)&lnb[c0];
        const float g[4] = {gv.x, gv.y, gv.z, gv.w};
        const float bb2[4] = {bv.x, bv.y, bv.z, bv.w};
        #pragma unroll
        for (int i = 0; i < 8; ++i) {
            const int n = n0 + r0 + i;
            const bool lig = (ntype[n] == 1);
            float4 y;
            if (lig) {
                const float mu  = s1[i] * (1.0f/256.0f);
                const float var = s2[i] * (1.0f/256.0f) - mu*mu;
                const float rs  = rsqrtf(var + 1e-5f);
                y.x = (acc[i][0] - mu) * rs * g[0] + bb2[0];
                y.y = (acc[i][1] - mu) * rs * g[1] + bb2[1];
                y.z = (acc[i][2] - mu) * rs * g[2] + bb2[2];
                y.w = (acc[i][3] - mu) * rs * g[3] + bb2[3];
            } else {
                y = hv[i];
            }
            *(float4*)&out[(size_t)n*HID + c0] = y;
        }
    }
}

// ===========================================================================
extern "C" void kernel_launch(void* const* d_in, const int* in_sizes, int n_in,
                              void* d_out, int out_size, void* d_ws, size_t ws_size,
                              hipStream_t stream) {
    (void)in_sizes; (void)n_in; (void)out_size;
    const float* h    = (const float*)d_in[0];
    const float* pos  = (const float*)d_in[1];
    const int*   ei   = (const int*)  d_in[2];
    const int*   et   = (const int*)  d_in[3];
    const int*   nt   = (const int*)  d_in[4];
    const float* emb  = (const float*)d_in[5];
    const float* W1m  = (const float*)d_in[6];
    const float* b1m  = (const float*)d_in[7];
    const float* W2m  = (const float*)d_in[8];
    const float* b2m  = (const float*)d_in[9];
    const float* W1u  = (const float*)d_in[10];
    const float* b1u  = (const float*)d_in[11];
    const float* W2u  = (const float*)d_in[12];
    const float* b2u  = (const float*)d_in[13];
    const float* lng  = (const float*)d_in[14];
    const float* lnb  = (const float*)d_in[15];
    float* out = (float*)d_out;

    // workspace layout (512B-aligned segments)
    size_t o = 0;
    auto al = [&](size_t b) { size_t r = o; o = (o + b + 511) & ~(size_t)511; return r; };
    const size_t o_seg  = al((size_t)NN * HID * 4);
    const size_t o_cnt  = al((size_t)NN * 4);
    const size_t o_zend = o;                       // memset range [0, o_zend)
    const size_t o_hpl  = al((size_t)2 * NN * HID * 2);
    const size_t o_emb  = al((size_t)2 * 2 * HID * 2);
    const size_t o_w1t  = al((size_t)2 * 256 * 544 * 2);
    const size_t o_w2t  = al((size_t)2 * 256 * 256 * 2);
    const size_t o_w1ut = al((size_t)2 * 256 * 512 * 2);
    const size_t o_w2ut = al((size_t)2 * 256 * 256 * 2);
    const size_t o_T    = al((size_t)2 * 256 * 4);
    const size_t o_mipl = al((size_t)2 * NN * HID * 2);
    const size_t o_upl  = al((size_t)NN * HID * 2);
    const size_t o_mhi  = al((size_t)EE * HID * 2);
    const size_t need = o;

    char* ws = (char*)d_ws;
    float* seg = (float*)(ws + o_seg);
    float* cnt = (float*)(ws + o_cnt);

    if (ws_size >= need) {
        short* hpl   = (short*)(ws + o_hpl);
        short* embpl = (short*)(ws + o_emb);
        short* w1t   = (short*)(ws + o_w1t);
        short* w2t   = (short*)(ws + o_w2t);
        short* w1ut  = (short*)(ws + o_w1ut);
        short* w2ut  = (short*)(ws + o_w2ut);
        float* T     = (float*)(ws + o_T);
        short* mipl  = (short*)(ws + o_mipl);
        short* upl   = (short*)(ws + o_upl);
        short* mhi   = (short*)(ws + o_mhi);

        hipMemsetAsync(d_ws, 0, o_zend, stream);
        prep_all<<<PREP_TOTAL / 256, 256, 0, stream>>>(
            h, emb, W1m, W2m, W1u, W2u, hpl, embpl, w1t, w2t, w1ut, w2ut);
        tprep<<<2, 256, 0, stream>>>(W1m, b1m, emb, T);
        edge_mlp1<<<dim3(EE / 128, 2), 512, 0, stream>>>(
            hpl, w1t, T, pos, ei, et, mhi, cnt);
        edge_mlp2<<<dim3(EE / 128, 2), 512, 0, stream>>>(mhi, w2t, b2m, ei, seg);
        mi_prep<<<(NN * HID) / 256, 256, 0, stream>>>(seg, cnt, mipl);
        const int nb = (NN + 127) / 128;
        node_mlp1<<<nb, 512, 0, stream>>>(hpl, mipl, w1ut, b1u, upl);
        node_mlp2<<<nb, 512, 0, stream>>>(upl, w2ut, b2u, h, nt, lng, lnb, out);
    } else {
        // fp32 fallback (round-1 kernels)
        hipMemsetAsync(d_ws, 0, ((size_t)NN * HID + NN) * sizeof(float), stream);
        float* seg0 = (float*)d_ws;
        float* cnt0 = seg0 + (size_t)NN * HID;
        edge_fp32<<<EE / 32, 256, 0, stream>>>(h, pos, ei, et, emb,
                                               W1m, b1m, W2m, b2m, seg0, cnt0);
        node_fp32<<<NN / 32, 256, 0, stream>>>(h, seg0, cnt0, nt,
                                               W1u, b1u, W2u, b2u, lng, lnb, out);
    }
}